// Round 1
// baseline (1475.879 us; speedup 1.0000x reference)
//
#include <hip/hip_runtime.h>
#include <math.h>

#define TT 1024
#define HID 7168
#define QL 1536
#define NH 64
#define DD 128
#define NQ (NH*DD)   // 8192
#define TOPK 512

// ---------------- workspace layout (in doubles) ----------------
// q:     TT*NQ      = 8,388,608
// kpart: 8*TT*192   = 1,572,864
// kk:    TT*DD      =   131,072
// wc:    TT*NH      =    65,536
// trig:  TT*64      =    65,536  (cos,sin interleaved per i<32)
#define OFF_Q     ((size_t)0)
#define OFF_KPART ((size_t)8388608)
#define OFF_KK    ((size_t)(8388608 + 1572864))
#define OFF_WC    ((size_t)(8388608 + 1572864 + 131072))
#define OFF_TRIG  ((size_t)(8388608 + 1572864 + 131072 + 65536))

// NEG = float32(-1e30) promoted to double, matching jnp.float32(-1e30)
#define NEGD ((double)(-1.0e30f))

__global__ void k_trig(const int* __restrict__ pos, double* __restrict__ trig) {
    int t = blockIdx.x;
    int i = threadIdx.x;           // 0..31
    double inv = 1.0 / pow(10000.0, (double)i / 32.0);
    double ang = (double)pos[t] * inv;
    trig[t*64 + 2*i]     = cos(ang);
    trig[t*64 + 2*i + 1] = sin(ang);
}

// q = qr @ wq_b  (fp64 accumulate).  Tile 128x64, TK=16, 256 threads, micro 8x4.
__global__ __launch_bounds__(256) void k_gemm_q(const float* __restrict__ qr,
                                                const float* __restrict__ wqb,
                                                double* __restrict__ q) {
    __shared__ double As[16][130];   // [kk][ml], pad 2 for banks/alignment
    __shared__ double Bs[16][66];    // [kk][nl]
    int tid = threadIdx.x;
    int tx = tid & 15, ty = tid >> 4;
    int m0 = blockIdx.y * 128, n0 = blockIdx.x * 64;
    double acc[8][4] = {};
    for (int k0 = 0; k0 < QL; k0 += 16) {
        #pragma unroll
        for (int u = 0; u < 8; ++u) {           // A: 128x16
            int e = tid + 256*u; int ml = e >> 4, kk = e & 15;
            As[kk][ml] = (double)qr[(size_t)(m0+ml)*QL + k0 + kk];
        }
        #pragma unroll
        for (int u = 0; u < 4; ++u) {           // B: 16x64
            int e = tid + 256*u; int kk = e >> 6, nl = e & 63;
            Bs[kk][nl] = (double)wqb[(size_t)(k0+kk)*NQ + n0 + nl];
        }
        __syncthreads();
        #pragma unroll
        for (int kk = 0; kk < 16; ++kk) {
            double a[8], b[4];
            #pragma unroll
            for (int i = 0; i < 8; ++i) a[i] = As[kk][ty + 16*i];
            #pragma unroll
            for (int j = 0; j < 4; ++j) b[j] = Bs[kk][tx + 16*j];
            #pragma unroll
            for (int i = 0; i < 8; ++i)
                #pragma unroll
                for (int j = 0; j < 4; ++j)
                    acc[i][j] = fma(a[i], b[j], acc[i][j]);
        }
        __syncthreads();
    }
    #pragma unroll
    for (int i = 0; i < 8; ++i)
        #pragma unroll
        for (int j = 0; j < 4; ++j)
            q[(size_t)(m0 + ty + 16*i)*NQ + n0 + tx + 16*j] = acc[i][j];
}

// Fused k (128 cols) + w_proj (64 cols) GEMM, split-K 8 ways, 16 rows/block.
__global__ __launch_bounds__(192) void k_kw(const float* __restrict__ hidden,
                                            const float* __restrict__ wk,
                                            const float* __restrict__ wp,
                                            double* __restrict__ kpart) {
    __shared__ double Hs[128][18];
    int tid = threadIdx.x;
    int rb = blockIdx.x & 63, ks = blockIdx.x >> 6;
    int r0 = rb*16, kbase0 = ks*896;
    double acc[16] = {};
    int c = tid;  // 0..191: <128 -> wk col, >=128 -> wp col
    for (int sc = 0; sc < 7; ++sc) {
        int kb = kbase0 + sc*128;
        for (int e = tid; e < 2048; e += 192) {
            int r = e >> 7, kq = e & 127;
            Hs[kq][r] = (double)hidden[(size_t)(r0+r)*HID + kb + kq];
        }
        __syncthreads();
        for (int kq = 0; kq < 128; ++kq) {
            double w = (c < 128) ? (double)wk[(size_t)(kb+kq)*DD + c]
                                 : (double)wp[(size_t)(kb+kq)*NH + (c-128)];
            #pragma unroll
            for (int r = 0; r < 16; ++r) acc[r] = fma(Hs[kq][r], w, acc[r]);
        }
        __syncthreads();
    }
    for (int r = 0; r < 16; ++r)
        kpart[(size_t)ks*TT*192 + (size_t)(r0+r)*192 + c] = acc[r];
}

// wc[t,h] = fl(fl(sum + b) * 128^-0.5) * 0.125   (q_scale folded out exactly)
__global__ void k_post_w(const double* __restrict__ kpart,
                         const float* __restrict__ bp,
                         double* __restrict__ wc) {
    int g = blockIdx.x*256 + threadIdx.x;   // < 65536
    int t = g >> 6, h = g & 63;
    double s = 0.0;
    for (int ks = 0; ks < 8; ++ks)
        s += kpart[(size_t)ks*TT*192 + (size_t)t*192 + 128 + h];
    s = s + (double)bp[h];
    s = s * 0.08838834764831845;   // 128**-0.5 (fp64)
    wc[t*64 + h] = s * 0.125;      // 64**-0.5 (exact pow2)
}

// reduce partials -> LayerNorm -> RoPE -> k final
__global__ __launch_bounds__(128) void k_post_k(const double* __restrict__ kpart,
                                                const float* __restrict__ kg,
                                                const float* __restrict__ kb,
                                                const double* __restrict__ trig,
                                                double* __restrict__ kkv) {
    __shared__ double red[128];
    __shared__ double row[128];
    int t = blockIdx.x, d = threadIdx.x;
    double v = 0.0;
    for (int ks = 0; ks < 8; ++ks)
        v += kpart[(size_t)ks*TT*192 + (size_t)t*192 + d];
    red[d] = v; __syncthreads();
    for (int off = 64; off; off >>= 1) { if (d < off) red[d] += red[d+off]; __syncthreads(); }
    double mu = red[0] / 128.0; __syncthreads();
    double diff = v - mu;
    red[d] = diff*diff; __syncthreads();
    for (int off = 64; off; off >>= 1) { if (d < off) red[d] += red[d+off]; __syncthreads(); }
    double var = red[0] / 128.0;
    double rsq = 1.0 / sqrt(var + 1e-6);
    double kn = ((v - mu) * rsq) * (double)kg[d] + (double)kb[d];
    row[d] = kn; __syncthreads();
    double outv;
    if (d < 32) {
        double c = trig[t*64 + 2*d], s = trig[t*64 + 2*d + 1];
        outv = row[d]*c - row[d+32]*s;
    } else if (d < 64) {
        int i = d - 32;
        double c = trig[t*64 + 2*i], s = trig[t*64 + 2*i + 1];
        outv = row[d]*c + row[d-32]*s;
    } else outv = kn;
    kkv[(size_t)t*DD + d] = outv;
}

// in-place neox RoPE on q[..., :64] per head
__global__ void k_rope_q(double* __restrict__ q, const double* __restrict__ trig) {
    int g = blockIdx.x*256 + threadIdx.x;   // T*H*32 = 2,097,152
    int t = g >> 11, rem = g & 2047, h = rem >> 5, i = rem & 31;
    size_t base = (size_t)t*NQ + (size_t)h*DD;
    double x1 = q[base + i], x2 = q[base + i + 32];
    double c = trig[t*64 + 2*i], s = trig[t*64 + 2*i + 1];
    q[base + i]      = x1*c - x2*s;
    q[base + i + 32] = x2*c + x1*s;
}

// per-row scores + causal mask + bitonic top-512 (desc value, asc index)
__global__ __launch_bounds__(256) void k_scores(const double* __restrict__ q,
                                                const double* __restrict__ kkv,
                                                const double* __restrict__ wc,
                                                const int* __restrict__ pos,
                                                float* __restrict__ out) {
    __shared__ double Qs[16][66];     // [dd][h]
    __shared__ double Ks[16][130];    // [dd][s]
    __shared__ double psum[128][9];
    __shared__ double svals[1024];
    __shared__ int    sidx[1024];
    int tid = threadIdx.x, t = blockIdx.x;
    int s_thr = tid & 31, h_thr = tid >> 5;   // 32 x 8
    int post = pos[t];
    for (int e = tid; e < 1024; e += 256) { svals[e] = NEGD; sidx[e] = e; }
    double w[8];
    #pragma unroll
    for (int j = 0; j < 8; ++j) w[j] = wc[t*64 + h_thr*8 + j];
    int niter = (t >> 7) + 1;    // causal: only s-tiles with s0 <= t
    for (int it = 0; it < niter; ++it) {
        int s0 = it << 7;
        double acc[4][8] = {};
        for (int dc = 0; dc < 8; ++dc) {
            int d0 = dc << 4;
            __syncthreads();
            #pragma unroll
            for (int u = 0; u < 4; ++u) {     // Qs: 16dd x 64h
                int e = tid + 256*u; int dd = e & 15, hh = e >> 4;
                Qs[dd][hh] = q[(size_t)t*NQ + (size_t)hh*DD + d0 + dd];
            }
            #pragma unroll
            for (int u = 0; u < 8; ++u) {     // Ks: 16dd x 128s
                int e = tid + 256*u; int dd = e & 15, ss = e >> 4;
                Ks[dd][ss] = kkv[(size_t)(s0+ss)*DD + d0 + dd];
            }
            __syncthreads();
            #pragma unroll
            for (int dd = 0; dd < 16; ++dd) {
                double kv[4], qv[8];
                #pragma unroll
                for (int i2 = 0; i2 < 4; ++i2) kv[i2] = Ks[dd][s_thr + 32*i2];
                #pragma unroll
                for (int j = 0; j < 8; ++j) qv[j] = Qs[dd][h_thr*8 + j];
                #pragma unroll
                for (int i2 = 0; i2 < 4; ++i2)
                    #pragma unroll
                    for (int j = 0; j < 8; ++j)
                        acc[i2][j] = fma(kv[i2], qv[j], acc[i2][j]);
            }
        }
        double part[4];
        #pragma unroll
        for (int i2 = 0; i2 < 4; ++i2) {
            double p = 0.0;
            #pragma unroll
            for (int j = 0; j < 8; ++j) p += fmax(acc[i2][j], 0.0) * w[j];
            part[i2] = p;
        }
        __syncthreads();
        #pragma unroll
        for (int i2 = 0; i2 < 4; ++i2) psum[s_thr + 32*i2][h_thr] = part[i2];
        __syncthreads();
        if (tid < 128) {
            int s = s0 + tid;
            double sc = 0.0;
            #pragma unroll
            for (int g2 = 0; g2 < 8; ++g2) sc += psum[tid][g2];  // h ascending
            svals[s] = (post >= pos[s]) ? sc : NEGD;
        }
    }
    __syncthreads();
    // bitonic sort, comparator: value desc, index asc
    for (int kk2 = 2; kk2 <= 1024; kk2 <<= 1) {
        for (int j = kk2 >> 1; j > 0; j >>= 1) {
            for (int i = tid; i < 1024; i += 256) {
                int l = i ^ j;
                if (l > i) {
                    double vi = svals[i], vl = svals[l];
                    int ii = sidx[i], il = sidx[l];
                    bool dir  = ((i & kk2) == 0);
                    bool lpre = (vl > vi) || (vl == vi && il < ii);
                    bool ipre = (vi > vl) || (vi == vl && ii < il);
                    if (dir ? lpre : ipre) {
                        svals[i]=vl; svals[l]=vi; sidx[i]=il; sidx[l]=ii;
                    }
                }
            }
            __syncthreads();
        }
    }
    for (int r = tid; r < TOPK; r += 256) {
        double v = svals[r];
        out[(size_t)t*TOPK + r] = (float)v;
        out[(size_t)TT*TOPK + (size_t)t*TOPK + r] =
            (v > 0.5*NEGD) ? (float)sidx[r] : -1.0f;
    }
}

extern "C" void kernel_launch(void* const* d_in, const int* in_sizes, int n_in,
                              void* d_out, int out_size, void* d_ws, size_t ws_size,
                              hipStream_t stream) {
    const float* hidden = (const float*)d_in[0];
    const float* qr     = (const float*)d_in[1];
    const float* wqb    = (const float*)d_in[2];
    const float* wk     = (const float*)d_in[3];
    const float* kg     = (const float*)d_in[4];
    const float* kb     = (const float*)d_in[5];
    const float* wp     = (const float*)d_in[6];
    const float* bp     = (const float*)d_in[7];
    const int*   pos    = (const int*)d_in[8];
    float* out = (float*)d_out;

    double* W     = (double*)d_ws;
    double* q     = W + OFF_Q;
    double* kpart = W + OFF_KPART;
    double* kkv   = W + OFF_KK;
    double* wc    = W + OFF_WC;
    double* trig  = W + OFF_TRIG;

    k_trig  <<<TT, 32, 0, stream>>>(pos, trig);
    k_gemm_q<<<dim3(NQ/64, TT/128), 256, 0, stream>>>(qr, wqb, q);
    k_kw    <<<512, 192, 0, stream>>>(hidden, wk, wp, kpart);
    k_post_w<<<(TT*NH)/256, 256, 0, stream>>>(kpart, bp, wc);
    k_post_k<<<TT, 128, 0, stream>>>(kpart, kg, kb, trig, kkv);
    k_rope_q<<<(TT*NH*32)/256, 256, 0, stream>>>(q, trig);
    k_scores<<<TT, 256, 0, stream>>>(q, kkv, wc, pos, out);
}

// Round 2
// 526.687 us; speedup vs baseline: 2.8022x; 2.8022x over previous
//
#include <hip/hip_runtime.h>
#include <math.h>

#define TT 1024
#define HID 7168
#define QL 1536
#define NH 64
#define DD 128
#define NQ 8192
#define TOPK 512
#define NEGF (-1.0e30f)

typedef float  f32x4 __attribute__((ext_vector_type(4)));
typedef short  s16x8 __attribute__((ext_vector_type(8)));
typedef short  s16x4 __attribute__((ext_vector_type(4)));

// ---- workspace byte offsets ----
#define OFF_QB    ((size_t)0)            // ushort q_bf16 [1024][8192]
#define OFF_WQBT  ((size_t)16777216)     // ushort wq_b^T bf16 [8192][1536]
#define OFF_QRB   ((size_t)41943040)     // ushort qr bf16 [1024][1536]
#define OFF_KPART ((size_t)45088768)     // float kpart [8][1024][192]
#define OFF_KKB   ((size_t)51380224)     // ushort k bf16 [1024][128]
#define OFF_WC    ((size_t)51642368)     // float wc [1024][64]
#define OFF_TRIG  ((size_t)51904512)     // float2 trig [1024][32]

__device__ __forceinline__ unsigned short f2bf(float x) {
  unsigned int u = __builtin_bit_cast(unsigned int, x);
  u = (u + 0x7FFFu + ((u >> 16) & 1u)) >> 16;
  return (unsigned short)u;
}

__device__ __forceinline__ s16x8 ld_frag(const unsigned short* p) {
  s16x4 lo = *(const s16x4*)p;
  s16x4 hi = *(const s16x4*)(p + 16);
  s16x8 r = { lo[0], lo[1], lo[2], lo[3], hi[0], hi[1], hi[2], hi[3] };
  return r;
}

__device__ __forceinline__ void cp16(unsigned short* dst, const unsigned short* src) {
  s16x8 v = *(const s16x8*)src;            // 16B global load
  s16x4 lo = { v[0], v[1], v[2], v[3] };
  s16x4 hi = { v[4], v[5], v[6], v[7] };
  *(s16x4*)dst = lo;                        // two 8B LDS stores (rows 8B-aligned)
  *(s16x4*)(dst + 4) = hi;
}

// ---------------- trig table: float2(cos,sin) at [t*32+i] ----------------
__global__ void k_trig(const int* __restrict__ pos, float2* __restrict__ trig) {
  int t = blockIdx.x, i = threadIdx.x;   // 32 threads
  double inv = pow(10000.0, -(double)i / 32.0);
  double ang = (double)pos[t] * inv;
  trig[t*32 + i] = make_float2((float)cos(ang), (float)sin(ang));
}

// ---------------- qr fp32 -> bf16 ----------------
__global__ void k_cvt(const float* __restrict__ in, unsigned short* __restrict__ out) {
  int i = (blockIdx.x*256 + threadIdx.x)*4;   // n = 1572864, divisible
  float4 v = *(const float4*)(in + i);
  s16x4 o = { (short)f2bf(v.x), (short)f2bf(v.y), (short)f2bf(v.z), (short)f2bf(v.w) };
  *(s16x4*)(out + i) = o;
}

// ---------------- wq_b [1536][8192] fp32 -> transposed bf16 [8192][1536] ----------------
__global__ __launch_bounds__(256) void k_trcvt(const float* __restrict__ in,
                                               unsigned short* __restrict__ outT) {
  __shared__ float tileS[64][65];
  int n0 = blockIdx.x*64, k0 = blockIdx.y*64;
  int tid = threadIdx.x;
  for (int c = tid; c < 1024; c += 256) {           // 64k x 64n floats
    int r = c >> 4, c4 = (c & 15)*4;
    float4 v = *(const float4*)(in + (size_t)(k0+r)*NQ + n0 + c4);
    tileS[r][c4] = v.x; tileS[r][c4+1] = v.y; tileS[r][c4+2] = v.z; tileS[r][c4+3] = v.w;
  }
  __syncthreads();
  for (int c = tid; c < 512; c += 256) {            // 64n rows x 8-chunks of k
    int rn = c >> 3, c8 = (c & 7)*8;
    s16x8 v;
    #pragma unroll
    for (int u = 0; u < 8; ++u) v[u] = (short)f2bf(tileS[c8+u][rn]);
    *(s16x8*)(outT + (size_t)(n0+rn)*QL + k0 + c8) = v;
  }
}

// ---------------- q = qr @ wq_b via bf16 MFMA, fused RoPE, bf16 out ----------------
__global__ __launch_bounds__(256) void k_gemm_q(const unsigned short* __restrict__ qrb,
                                                const unsigned short* __restrict__ wqbt,
                                                const float2* __restrict__ trig,
                                                unsigned short* __restrict__ qb) {
  __shared__ unsigned short As[128*68];   // A[m][k] pad4
  __shared__ unsigned short Bs[128*68];   // B^T[n][k] pad4
  int tid = threadIdx.x;
  int w = tid >> 6, wr = w >> 1, wc = w & 1, l = tid & 63, lg = l >> 4, lm = l & 15;
  int m0 = blockIdx.y*128, n0 = blockIdx.x*128;
  f32x4 acc[4][4] = {};   // [m-tile][n-tile]
  for (int k0 = 0; k0 < QL; k0 += 64) {
    __syncthreads();
    for (int c = tid; c < 2048; c += 256) {    // 256 rows (128 A + 128 B) x 8 chunks
      int row = c >> 3, col8 = (c & 7)*8;
      if (row < 128)
        cp16(&As[row*68 + col8], qrb  + (size_t)(m0+row)*QL + k0 + col8);
      else
        cp16(&Bs[(row-128)*68 + col8], wqbt + (size_t)(n0+row-128)*QL + k0 + col8);
    }
    __syncthreads();
    #pragma unroll
    for (int kk = 0; kk < 2; ++kk) {
      int kb = kk*32 + 4*lg;
      s16x8 af[4], bf[4];
      #pragma unroll
      for (int i = 0; i < 4; ++i) af[i] = ld_frag(&As[(wr*64 + i*16 + lm)*68 + kb]);
      #pragma unroll
      for (int j = 0; j < 4; ++j) bf[j] = ld_frag(&Bs[(wc*64 + j*16 + lm)*68 + kb]);
      #pragma unroll
      for (int i = 0; i < 4; ++i)
        #pragma unroll
        for (int j = 0; j < 4; ++j)
          acc[i][j] = __builtin_amdgcn_mfma_f32_16x16x32_bf16(af[i], bf[j], acc[i][j], 0, 0, 0);
    }
  }
  // epilogue: RoPE on cols<64 of the head (wc==0), then bf16 store
  #pragma unroll
  for (int i = 0; i < 4; ++i) {
    int trow = m0 + wr*64 + i*16 + lg*4;
    if (wc == 0) {
      #pragma unroll
      for (int r = 0; r < 4; ++r) {
        int t = trow + r;
        #pragma unroll
        for (int jj = 0; jj < 2; ++jj) {
          int idx = jj*16 + lm;
          float2 cs = trig[t*32 + idx];
          float x1 = acc[i][jj][r], x2 = acc[i][jj+2][r];
          acc[i][jj][r]   = x1*cs.x - x2*cs.y;
          acc[i][jj+2][r] = x2*cs.x + x1*cs.y;
        }
      }
    }
    #pragma unroll
    for (int j = 0; j < 4; ++j)
      #pragma unroll
      for (int r = 0; r < 4; ++r)
        qb[(size_t)(trow + r)*NQ + n0 + wc*64 + j*16 + lm] = f2bf(acc[i][j][r]);
  }
}

// ---------------- fused k + w_proj GEMM (fp32, split-K 8) ----------------
__global__ __launch_bounds__(192) void k_kw(const float* __restrict__ hidden,
                                            const float* __restrict__ wk,
                                            const float* __restrict__ wp,
                                            float* __restrict__ kpart) {
  __shared__ float Hs[128][17];
  int tid = threadIdx.x;
  int rb = blockIdx.x & 63, ks = blockIdx.x >> 6;
  int r0 = rb*16, kbase0 = ks*896;
  float acc[16] = {};
  int c = tid;
  for (int sc = 0; sc < 7; ++sc) {
    int kb = kbase0 + sc*128;
    for (int e = tid; e < 2048; e += 192) {
      int r = e >> 7, kq = e & 127;
      Hs[kq][r] = hidden[(size_t)(r0+r)*HID + kb + kq];
    }
    __syncthreads();
    for (int kq = 0; kq < 128; ++kq) {
      float wv = (c < 128) ? wk[(size_t)(kb+kq)*DD + c]
                           : wp[(size_t)(kb+kq)*NH + (c-128)];
      #pragma unroll
      for (int r = 0; r < 16; ++r) acc[r] = fmaf(Hs[kq][r], wv, acc[r]);
    }
    __syncthreads();
  }
  for (int r = 0; r < 16; ++r)
    kpart[(size_t)ks*TT*192 + (size_t)(r0+r)*192 + c] = acc[r];
}

// ---------------- wc[t,h] ----------------
__global__ void k_post_w(const float* __restrict__ kpart,
                         const float* __restrict__ bp,
                         float* __restrict__ wcq) {
  int g = blockIdx.x*256 + threadIdx.x;   // 65536
  int t = g >> 6, h = g & 63;
  float s = 0.f;
  for (int ks = 0; ks < 8; ++ks)
    s += kpart[(size_t)ks*TT*192 + (size_t)t*192 + 128 + h];
  s = (s + bp[h]) * 0.08838834764831845f;  // 128^-0.5
  wcq[t*64 + h] = s * 0.125f;              // 64^-0.5
}

// ---------------- k partials -> LN -> RoPE -> bf16 ----------------
__global__ __launch_bounds__(128) void k_post_k(const float* __restrict__ kpart,
                                                const float* __restrict__ kg,
                                                const float* __restrict__ kb,
                                                const float2* __restrict__ trig,
                                                unsigned short* __restrict__ kkb) {
  __shared__ float red[128];
  __shared__ float row[128];
  int t = blockIdx.x, d = threadIdx.x;
  float v = 0.f;
  for (int ks = 0; ks < 8; ++ks)
    v += kpart[(size_t)ks*TT*192 + (size_t)t*192 + d];
  red[d] = v; __syncthreads();
  for (int off = 64; off; off >>= 1) { if (d < off) red[d] += red[d+off]; __syncthreads(); }
  float mu = red[0] * (1.f/128.f); __syncthreads();
  float diff = v - mu;
  red[d] = diff*diff; __syncthreads();
  for (int off = 64; off; off >>= 1) { if (d < off) red[d] += red[d+off]; __syncthreads(); }
  float var = red[0] * (1.f/128.f);
  float rsq = 1.f / sqrtf(var + 1e-6f);
  float kn = (v - mu) * rsq * kg[d] + kb[d];
  row[d] = kn; __syncthreads();
  float outv;
  if (d < 32) {
    float2 cs = trig[t*32 + d];
    outv = row[d]*cs.x - row[d+32]*cs.y;
  } else if (d < 64) {
    float2 cs = trig[t*32 + d - 32];
    outv = row[d]*cs.x + row[d-32]*cs.y;
  } else outv = kn;
  kkb[(size_t)t*DD + d] = f2bf(outv);
}

// ---------------- scores (bf16 MFMA) + mask + bitonic top-512 ----------------
__global__ __launch_bounds__(256) void k_scores(const unsigned short* __restrict__ qb,
                                                const unsigned short* __restrict__ kkb,
                                                const float* __restrict__ wcq,
                                                const int* __restrict__ pos,
                                                float* __restrict__ out) {
  __shared__ unsigned short Qs[64*132];    // Q[h][d] pad4
  __shared__ unsigned short Ks[128*132];   // K[s][d] pad4
  __shared__ float svals[1024];
  __shared__ int   sidx[1024];
  int tid = threadIdx.x, t = blockIdx.x;
  int w = tid >> 6, l = tid & 63, lg = l >> 4, lm = l & 15;
  for (int e = tid; e < 1024; e += 256) { svals[e] = NEGF; sidx[e] = e; }
  for (int c = tid; c < 1024; c += 256) {          // stage Q: 64h x 16 chunks
    int h = c >> 4, d8 = (c & 15)*8;
    cp16(&Qs[h*132 + d8], qb + (size_t)t*NQ + h*DD + d8);
  }
  float wreg[4];
  #pragma unroll
  for (int j = 0; j < 4; ++j) wreg[j] = wcq[t*64 + j*16 + lm];
  int post = pos[t];
  int niter = (t >> 7) + 1;
  for (int it = 0; it < niter; ++it) {
    int s0 = it << 7;
    __syncthreads();
    for (int c = tid; c < 2048; c += 256) {        // stage K: 128s x 16 chunks
      int s = c >> 4, d8 = (c & 15)*8;
      cp16(&Ks[s*132 + d8], kkb + (size_t)(s0+s)*DD + d8);
    }
    __syncthreads();
    f32x4 acc[2][4] = {};
    #pragma unroll
    for (int ksb = 0; ksb < 4; ++ksb) {            // d in steps of 32
      int kbd = ksb*32 + 4*lg;
      s16x8 af[2], bf[4];
      #pragma unroll
      for (int i2 = 0; i2 < 2; ++i2) af[i2] = ld_frag(&Ks[(w*32 + i2*16 + lm)*132 + kbd]);
      #pragma unroll
      for (int j = 0; j < 4; ++j) bf[j] = ld_frag(&Qs[(j*16 + lm)*132 + kbd]);
      #pragma unroll
      for (int i2 = 0; i2 < 2; ++i2)
        #pragma unroll
        for (int j = 0; j < 4; ++j)
          acc[i2][j] = __builtin_amdgcn_mfma_f32_16x16x32_bf16(af[i2], bf[j], acc[i2][j], 0, 0, 0);
    }
    #pragma unroll
    for (int i2 = 0; i2 < 2; ++i2)
      #pragma unroll
      for (int r = 0; r < 4; ++r) {
        float p = 0.f;
        #pragma unroll
        for (int j = 0; j < 4; ++j) p += fmaxf(acc[i2][j][r], 0.f) * wreg[j];
        p += __shfl_xor(p, 1); p += __shfl_xor(p, 2);
        p += __shfl_xor(p, 4); p += __shfl_xor(p, 8);
        if (lm == 0) {
          int s = s0 + w*32 + i2*16 + lg*4 + r;
          svals[s] = (post >= pos[s]) ? p : NEGF;
        }
      }
  }
  __syncthreads();
  for (int kk2 = 2; kk2 <= 1024; kk2 <<= 1) {
    for (int j = kk2 >> 1; j > 0; j >>= 1) {
      for (int i = tid; i < 1024; i += 256) {
        int lpp = i ^ j;
        if (lpp > i) {
          float vi = svals[i], vl = svals[lpp];
          int ii = sidx[i], il = sidx[lpp];
          bool dir  = ((i & kk2) == 0);
          bool lpre = (vl > vi) || (vl == vi && il < ii);
          bool ipre = (vi > vl) || (vi == vl && ii < il);
          if (dir ? lpre : ipre) {
            svals[i]=vl; svals[lpp]=vi; sidx[i]=il; sidx[lpp]=ii;
          }
        }
      }
      __syncthreads();
    }
  }
  for (int r = tid; r < TOPK; r += 256) {
    float v = svals[r];
    out[(size_t)t*TOPK + r] = v;
    out[(size_t)TT*TOPK + (size_t)t*TOPK + r] = (v > 0.5f*NEGF) ? (float)sidx[r] : -1.0f;
  }
}

extern "C" void kernel_launch(void* const* d_in, const int* in_sizes, int n_in,
                              void* d_out, int out_size, void* d_ws, size_t ws_size,
                              hipStream_t stream) {
  const float* hidden = (const float*)d_in[0];
  const float* qr     = (const float*)d_in[1];
  const float* wqb    = (const float*)d_in[2];
  const float* wk     = (const float*)d_in[3];
  const float* kg     = (const float*)d_in[4];
  const float* kb     = (const float*)d_in[5];
  const float* wp     = (const float*)d_in[6];
  const float* bp     = (const float*)d_in[7];
  const int*   pos    = (const int*)d_in[8];
  float* out = (float*)d_out;

  char* W = (char*)d_ws;
  unsigned short* qbuf  = (unsigned short*)(W + OFF_QB);
  unsigned short* wqbt  = (unsigned short*)(W + OFF_WQBT);
  unsigned short* qrb   = (unsigned short*)(W + OFF_QRB);
  float*          kpart = (float*)(W + OFF_KPART);
  unsigned short* kkbuf = (unsigned short*)(W + OFF_KKB);
  float*          wcq   = (float*)(W + OFF_WC);
  float2*         trig  = (float2*)(W + OFF_TRIG);

  k_trig  <<<TT, 32, 0, stream>>>(pos, trig);
  k_cvt   <<<(TT*QL)/1024, 256, 0, stream>>>(qr, qrb);
  k_trcvt <<<dim3(NQ/64, QL/64), 256, 0, stream>>>(wqb, wqbt);
  k_gemm_q<<<dim3(NQ/128, TT/128), 256, 0, stream>>>(qrb, wqbt, trig, qbuf);
  k_kw    <<<512, 192, 0, stream>>>(hidden, wk, wp, kpart);
  k_post_w<<<(TT*NH)/256, 256, 0, stream>>>(kpart, bp, wcq);
  k_post_k<<<TT, 128, 0, stream>>>(kpart, kg, kb, trig, kkbuf);
  k_scores<<<TT, 256, 0, stream>>>(qbuf, kkbuf, wcq, pos, out);
}

// Round 3
// 422.178 us; speedup vs baseline: 3.4959x; 1.2475x over previous
//
#include <hip/hip_runtime.h>
#include <math.h>

#define TT 1024
#define HID 7168
#define QL 1536
#define NH 64
#define DD 128
#define NQ 8192
#define TOPK 512
#define NEGF (-1.0e30f)

typedef float  f32x4 __attribute__((ext_vector_type(4)));
typedef short  s16x8 __attribute__((ext_vector_type(8)));
typedef short  s16x4 __attribute__((ext_vector_type(4)));

// ---- workspace byte offsets ----
#define OFF_QB    ((size_t)0)            // ushort q_bf16 [1024][8192]
#define OFF_WQBT  ((size_t)16777216)     // ushort wq_b^T bf16 [8192][1536]
#define OFF_QRB   ((size_t)41943040)     // ushort qr bf16 [1024][1536]
#define OFF_KPART ((size_t)45088768)     // float kpart [8][1024][192]
#define OFF_KKB   ((size_t)51380224)     // ushort k bf16 [1024][128]
#define OFF_WC    ((size_t)51642368)     // float wc [1024][64]
#define OFF_TRIG  ((size_t)51904512)     // float2 trig [1024][32]
#define OFF_HB    ((size_t)52166656)     // ushort hidden bf16 [1024][7168]
#define OFF_WKPT  ((size_t)66846720)     // ushort [wk|wp]^T bf16 [192][7168]

__device__ __forceinline__ unsigned short f2bf(float x) {
  unsigned int u = __builtin_bit_cast(unsigned int, x);
  u = (u + 0x7FFFu + ((u >> 16) & 1u)) >> 16;
  return (unsigned short)u;
}

__device__ __forceinline__ s16x8 ld_frag(const unsigned short* p) {
  s16x4 lo = *(const s16x4*)p;
  s16x4 hi = *(const s16x4*)(p + 16);
  s16x8 r = { lo[0], lo[1], lo[2], lo[3], hi[0], hi[1], hi[2], hi[3] };
  return r;
}

__device__ __forceinline__ void cp16(unsigned short* dst, const unsigned short* src) {
  s16x8 v = *(const s16x8*)src;            // 16B global load
  s16x4 lo = { v[0], v[1], v[2], v[3] };
  s16x4 hi = { v[4], v[5], v[6], v[7] };
  *(s16x4*)dst = lo;                        // two 8B LDS stores (rows 8B-aligned)
  *(s16x4*)(dst + 4) = hi;
}

// ---------------- trig table: float2(cos,sin) at [t*32+i] ----------------
__global__ void k_trig(const int* __restrict__ pos, float2* __restrict__ trig) {
  int t = blockIdx.x, i = threadIdx.x;   // 32 threads
  double inv = pow(10000.0, -(double)i / 32.0);
  double ang = (double)pos[t] * inv;
  trig[t*32 + i] = make_float2((float)cos(ang), (float)sin(ang));
}

// ---------------- fp32 -> bf16 (n divisible by 1024) ----------------
__global__ void k_cvt(const float* __restrict__ in, unsigned short* __restrict__ out) {
  int i = (blockIdx.x*256 + threadIdx.x)*4;
  float4 v = *(const float4*)(in + i);
  s16x4 o = { (short)f2bf(v.x), (short)f2bf(v.y), (short)f2bf(v.z), (short)f2bf(v.w) };
  *(s16x4*)(out + i) = o;
}

// ---------------- wq_b [1536][8192] fp32 -> transposed bf16 [8192][1536] ----------------
__global__ __launch_bounds__(256) void k_trcvt(const float* __restrict__ in,
                                               unsigned short* __restrict__ outT) {
  __shared__ float tileS[64][65];
  int n0 = blockIdx.x*64, k0 = blockIdx.y*64;
  int tid = threadIdx.x;
  for (int c = tid; c < 1024; c += 256) {           // 64k x 64n floats
    int r = c >> 4, c4 = (c & 15)*4;
    float4 v = *(const float4*)(in + (size_t)(k0+r)*NQ + n0 + c4);
    tileS[r][c4] = v.x; tileS[r][c4+1] = v.y; tileS[r][c4+2] = v.z; tileS[r][c4+3] = v.w;
  }
  __syncthreads();
  for (int c = tid; c < 512; c += 256) {            // 64n rows x 8-chunks of k
    int rn = c >> 3, c8 = (c & 7)*8;
    s16x8 v;
    #pragma unroll
    for (int u = 0; u < 8; ++u) v[u] = (short)f2bf(tileS[c8+u][rn]);
    *(s16x8*)(outT + (size_t)(n0+rn)*QL + k0 + c8) = v;
  }
}

// ---------------- wk [7168][128] + wp [7168][64] -> [192][7168] bf16 ----------------
__global__ __launch_bounds__(256) void k_trkw(const float* __restrict__ wk,
                                              const float* __restrict__ wp,
                                              unsigned short* __restrict__ wkpT) {
  __shared__ float tileS[64][65];
  int bx = blockIdx.x;                // 0,1 -> wk col-tiles; 2 -> wp
  int k0 = blockIdx.y*64;
  int tid = threadIdx.x;
  const float* src; int stride, c0;
  if (bx < 2) { src = wk; stride = DD; c0 = bx*64; }
  else        { src = wp; stride = NH; c0 = 0; }
  for (int c = tid; c < 1024; c += 256) {
    int r = c >> 4, c4 = (c & 15)*4;
    float4 v = *(const float4*)(src + (size_t)(k0+r)*stride + c0 + c4);
    tileS[r][c4] = v.x; tileS[r][c4+1] = v.y; tileS[r][c4+2] = v.z; tileS[r][c4+3] = v.w;
  }
  __syncthreads();
  int rowOff = bx*64;
  for (int c = tid; c < 512; c += 256) {
    int rn = c >> 3, c8 = (c & 7)*8;
    s16x8 v;
    #pragma unroll
    for (int u = 0; u < 8; ++u) v[u] = (short)f2bf(tileS[c8+u][rn]);
    *(s16x8*)(wkpT + (size_t)(rowOff+rn)*HID + k0 + c8) = v;
  }
}

// ---------------- q = qr @ wq_b via bf16 MFMA, fused RoPE, bf16 out ----------------
__global__ __launch_bounds__(256) void k_gemm_q(const unsigned short* __restrict__ qrb,
                                                const unsigned short* __restrict__ wqbt,
                                                const float2* __restrict__ trig,
                                                unsigned short* __restrict__ qb) {
  __shared__ unsigned short As[128*68];   // A[m][k] pad4
  __shared__ unsigned short Bs[128*68];   // B^T[n][k] pad4
  int tid = threadIdx.x;
  int w = tid >> 6, wr = w >> 1, wc = w & 1, l = tid & 63, lg = l >> 4, lm = l & 15;
  int m0 = blockIdx.y*128, n0 = blockIdx.x*128;
  f32x4 acc[4][4] = {};   // [m-tile][n-tile]
  for (int k0 = 0; k0 < QL; k0 += 64) {
    __syncthreads();
    for (int c = tid; c < 2048; c += 256) {    // 256 rows (128 A + 128 B) x 8 chunks
      int row = c >> 3, col8 = (c & 7)*8;
      if (row < 128)
        cp16(&As[row*68 + col8], qrb  + (size_t)(m0+row)*QL + k0 + col8);
      else
        cp16(&Bs[(row-128)*68 + col8], wqbt + (size_t)(n0+row-128)*QL + k0 + col8);
    }
    __syncthreads();
    #pragma unroll
    for (int kk = 0; kk < 2; ++kk) {
      int kb = kk*32 + 4*lg;
      s16x8 af[4], bfr[4];
      #pragma unroll
      for (int i = 0; i < 4; ++i) af[i] = ld_frag(&As[(wr*64 + i*16 + lm)*68 + kb]);
      #pragma unroll
      for (int j = 0; j < 4; ++j) bfr[j] = ld_frag(&Bs[(wc*64 + j*16 + lm)*68 + kb]);
      #pragma unroll
      for (int i = 0; i < 4; ++i)
        #pragma unroll
        for (int j = 0; j < 4; ++j)
          acc[i][j] = __builtin_amdgcn_mfma_f32_16x16x32_bf16(af[i], bfr[j], acc[i][j], 0, 0, 0);
    }
  }
  #pragma unroll
  for (int i = 0; i < 4; ++i) {
    int trow = m0 + wr*64 + i*16 + lg*4;
    if (wc == 0) {
      #pragma unroll
      for (int r = 0; r < 4; ++r) {
        int t = trow + r;
        #pragma unroll
        for (int jj = 0; jj < 2; ++jj) {
          int idx = jj*16 + lm;
          float2 cs = trig[t*32 + idx];
          float x1 = acc[i][jj][r], x2 = acc[i][jj+2][r];
          acc[i][jj][r]   = x1*cs.x - x2*cs.y;
          acc[i][jj+2][r] = x2*cs.x + x1*cs.y;
        }
      }
    }
    #pragma unroll
    for (int j = 0; j < 4; ++j)
      #pragma unroll
      for (int r = 0; r < 4; ++r)
        qb[(size_t)(trow + r)*NQ + n0 + wc*64 + j*16 + lm] = f2bf(acc[i][j][r]);
  }
}

// ---------------- fused k + w_proj GEMM via bf16 MFMA, split-K 8 ----------------
__global__ __launch_bounds__(256) void k_kw_mfma(const unsigned short* __restrict__ hb,
                                                 const unsigned short* __restrict__ wkpT,
                                                 float* __restrict__ kpart) {
  __shared__ unsigned short As[32*68];
  __shared__ unsigned short Bs[192*68];
  int tid = threadIdx.x;
  int w = tid >> 6, l = tid & 63, lg = l >> 4, lm = l & 15;
  int ks = blockIdx.x, m0 = blockIdx.y*32;
  int kbase = ks*896;
  f32x4 acc[2][3] = {};
  for (int k0 = 0; k0 < 896; k0 += 64) {
    __syncthreads();
    for (int c = tid; c < 1792; c += 256) {     // 224 rows x 8 chunks of 8 ushorts
      int row = c >> 3, col8 = (c & 7)*8;
      if (row < 32)
        cp16(&As[row*68 + col8], hb + (size_t)(m0+row)*HID + kbase + k0 + col8);
      else
        cp16(&Bs[(row-32)*68 + col8], wkpT + (size_t)(row-32)*HID + kbase + k0 + col8);
    }
    __syncthreads();
    #pragma unroll
    for (int kk = 0; kk < 2; ++kk) {
      int kb = kk*32 + 4*lg;
      s16x8 af[2], bfr[3];
      #pragma unroll
      for (int i = 0; i < 2; ++i) af[i] = ld_frag(&As[(i*16 + lm)*68 + kb]);
      #pragma unroll
      for (int j = 0; j < 3; ++j) bfr[j] = ld_frag(&Bs[(w*48 + j*16 + lm)*68 + kb]);
      #pragma unroll
      for (int i = 0; i < 2; ++i)
        #pragma unroll
        for (int j = 0; j < 3; ++j)
          acc[i][j] = __builtin_amdgcn_mfma_f32_16x16x32_bf16(af[i], bfr[j], acc[i][j], 0, 0, 0);
    }
  }
  #pragma unroll
  for (int i = 0; i < 2; ++i)
    #pragma unroll
    for (int j = 0; j < 3; ++j)
      #pragma unroll
      for (int r = 0; r < 4; ++r) {
        int row = m0 + i*16 + lg*4 + r, col = w*48 + j*16 + lm;
        kpart[(size_t)ks*TT*192 + (size_t)row*192 + col] = acc[i][j][r];
      }
}

// ---------------- wc[t,h] ----------------
__global__ void k_post_w(const float* __restrict__ kpart,
                         const float* __restrict__ bp,
                         float* __restrict__ wcq) {
  int g = blockIdx.x*256 + threadIdx.x;   // 65536
  int t = g >> 6, h = g & 63;
  float s = 0.f;
  for (int ks = 0; ks < 8; ++ks)
    s += kpart[(size_t)ks*TT*192 + (size_t)t*192 + 128 + h];
  s = (s + bp[h]) * 0.08838834764831845f;  // 128^-0.5
  wcq[t*64 + h] = s * 0.125f;              // 64^-0.5
}

// ---------------- k partials -> LN -> RoPE -> bf16 ----------------
__global__ __launch_bounds__(128) void k_post_k(const float* __restrict__ kpart,
                                                const float* __restrict__ kg,
                                                const float* __restrict__ kb,
                                                const float2* __restrict__ trig,
                                                unsigned short* __restrict__ kkb) {
  __shared__ float red[128];
  __shared__ float row[128];
  int t = blockIdx.x, d = threadIdx.x;
  float v = 0.f;
  for (int ks = 0; ks < 8; ++ks)
    v += kpart[(size_t)ks*TT*192 + (size_t)t*192 + d];
  red[d] = v; __syncthreads();
  for (int off = 64; off; off >>= 1) { if (d < off) red[d] += red[d+off]; __syncthreads(); }
  float mu = red[0] * (1.f/128.f); __syncthreads();
  float diff = v - mu;
  red[d] = diff*diff; __syncthreads();
  for (int off = 64; off; off >>= 1) { if (d < off) red[d] += red[d+off]; __syncthreads(); }
  float var = red[0] * (1.f/128.f);
  float rsq = 1.f / sqrtf(var + 1e-6f);
  float kn = (v - mu) * rsq * kg[d] + kb[d];
  row[d] = kn; __syncthreads();
  float outv;
  if (d < 32) {
    float2 cs = trig[t*32 + d];
    outv = row[d]*cs.x - row[d+32]*cs.y;
  } else if (d < 64) {
    float2 cs = trig[t*32 + d - 32];
    outv = row[d]*cs.x + row[d-32]*cs.y;
  } else outv = kn;
  kkb[(size_t)t*DD + d] = f2bf(outv);
}

// ---------------- scores (bf16 MFMA) + mask + bitonic top-512 ----------------
__global__ __launch_bounds__(256) void k_scores(const unsigned short* __restrict__ qb,
                                                const unsigned short* __restrict__ kkb,
                                                const float* __restrict__ wcq,
                                                const int* __restrict__ pos,
                                                float* __restrict__ out) {
  __shared__ unsigned short Qs[64*132];    // Q[h][d] pad4
  __shared__ unsigned short Ks[128*132];   // K[s][d] pad4
  __shared__ float svals[1024];
  __shared__ int   sidx[1024];
  int tid = threadIdx.x, t = blockIdx.x;
  int w = tid >> 6, l = tid & 63, lg = l >> 4, lm = l & 15;
  for (int e = tid; e < 1024; e += 256) { svals[e] = NEGF; sidx[e] = e; }
  for (int c = tid; c < 1024; c += 256) {          // stage Q: 64h x 16 chunks
    int h = c >> 4, d8 = (c & 15)*8;
    cp16(&Qs[h*132 + d8], qb + (size_t)t*NQ + h*DD + d8);
  }
  float wreg[4];
  #pragma unroll
  for (int j = 0; j < 4; ++j) wreg[j] = wcq[t*64 + j*16 + lm];
  int post = pos[t];
  int niter = (t >> 7) + 1;
  for (int it = 0; it < niter; ++it) {
    int s0 = it << 7;
    __syncthreads();
    for (int c = tid; c < 2048; c += 256) {        // stage K: 128s x 16 chunks
      int s = c >> 4, d8 = (c & 15)*8;
      cp16(&Ks[s*132 + d8], kkb + (size_t)(s0+s)*DD + d8);
    }
    __syncthreads();
    f32x4 acc[2][4] = {};
    #pragma unroll
    for (int ksb = 0; ksb < 4; ++ksb) {            // d in steps of 32
      int kbd = ksb*32 + 4*lg;
      s16x8 af[2], bfr[4];
      #pragma unroll
      for (int i2 = 0; i2 < 2; ++i2) af[i2] = ld_frag(&Ks[(w*32 + i2*16 + lm)*132 + kbd]);
      #pragma unroll
      for (int j = 0; j < 4; ++j) bfr[j] = ld_frag(&Qs[(j*16 + lm)*132 + kbd]);
      #pragma unroll
      for (int i2 = 0; i2 < 2; ++i2)
        #pragma unroll
        for (int j = 0; j < 4; ++j)
          acc[i2][j] = __builtin_amdgcn_mfma_f32_16x16x32_bf16(af[i2], bfr[j], acc[i2][j], 0, 0, 0);
    }
    #pragma unroll
    for (int i2 = 0; i2 < 2; ++i2)
      #pragma unroll
      for (int r = 0; r < 4; ++r) {
        float p = 0.f;
        #pragma unroll
        for (int j = 0; j < 4; ++j) p += fmaxf(acc[i2][j][r], 0.f) * wreg[j];
        p += __shfl_xor(p, 1); p += __shfl_xor(p, 2);
        p += __shfl_xor(p, 4); p += __shfl_xor(p, 8);
        if (lm == 0) {
          int s = s0 + w*32 + i2*16 + lg*4 + r;
          svals[s] = (post >= pos[s]) ? p : NEGF;
        }
      }
  }
  __syncthreads();
  for (int kk2 = 2; kk2 <= 1024; kk2 <<= 1) {
    for (int j = kk2 >> 1; j > 0; j >>= 1) {
      for (int i = tid; i < 1024; i += 256) {
        int lpp = i ^ j;
        if (lpp > i) {
          float vi = svals[i], vl = svals[lpp];
          int ii = sidx[i], il = sidx[lpp];
          bool dir  = ((i & kk2) == 0);
          bool lpre = (vl > vi) || (vl == vi && il < ii);
          bool ipre = (vi > vl) || (vi == vl && ii < il);
          if (dir ? lpre : ipre) {
            svals[i]=vl; svals[lpp]=vi; sidx[i]=il; sidx[lpp]=ii;
          }
        }
      }
      __syncthreads();
    }
  }
  for (int r = tid; r < TOPK; r += 256) {
    float v = svals[r];
    out[(size_t)t*TOPK + r] = v;
    out[(size_t)TT*TOPK + (size_t)t*TOPK + r] = (v > 0.5f*NEGF) ? (float)sidx[r] : -1.0f;
  }
}

extern "C" void kernel_launch(void* const* d_in, const int* in_sizes, int n_in,
                              void* d_out, int out_size, void* d_ws, size_t ws_size,
                              hipStream_t stream) {
  const float* hidden = (const float*)d_in[0];
  const float* qr     = (const float*)d_in[1];
  const float* wqb    = (const float*)d_in[2];
  const float* wk     = (const float*)d_in[3];
  const float* kg     = (const float*)d_in[4];
  const float* kb     = (const float*)d_in[5];
  const float* wp     = (const float*)d_in[6];
  const float* bp     = (const float*)d_in[7];
  const int*   pos    = (const int*)d_in[8];
  float* out = (float*)d_out;

  char* W = (char*)d_ws;
  unsigned short* qbuf  = (unsigned short*)(W + OFF_QB);
  unsigned short* wqbt  = (unsigned short*)(W + OFF_WQBT);
  unsigned short* qrb   = (unsigned short*)(W + OFF_QRB);
  float*          kpart = (float*)(W + OFF_KPART);
  unsigned short* kkbuf = (unsigned short*)(W + OFF_KKB);
  float*          wcq   = (float*)(W + OFF_WC);
  float2*         trig  = (float2*)(W + OFF_TRIG);
  unsigned short* hb    = (unsigned short*)(W + OFF_HB);
  unsigned short* wkpT  = (unsigned short*)(W + OFF_WKPT);

  k_trig   <<<TT, 32, 0, stream>>>(pos, trig);
  k_cvt    <<<(TT*QL)/1024, 256, 0, stream>>>(qr, qrb);
  k_cvt    <<<(TT*HID)/1024, 256, 0, stream>>>(hidden, hb);
  k_trcvt  <<<dim3(NQ/64, QL/64), 256, 0, stream>>>(wqb, wqbt);
  k_trkw   <<<dim3(3, HID/64), 256, 0, stream>>>(wk, wp, wkpT);
  k_gemm_q <<<dim3(NQ/128, TT/128), 256, 0, stream>>>(qrb, wqbt, trig, qbuf);
  k_kw_mfma<<<dim3(8, TT/32), 256, 0, stream>>>(hb, wkpT, kpart);
  k_post_w <<<(TT*NH)/256, 256, 0, stream>>>(kpart, bp, wcq);
  k_post_k <<<TT, 128, 0, stream>>>(kpart, kg, kb, trig, kkbuf);
  k_scores <<<TT, 256, 0, stream>>>(qbuf, kkbuf, wcq, pos, out);
}

// Round 5
// 354.600 us; speedup vs baseline: 4.1621x; 1.1906x over previous
//
#include <hip/hip_runtime.h>
#include <math.h>

#define TT 1024
#define HID 7168
#define QL 1536
#define NH 64
#define DD 128
#define NQ 8192
#define TOPK 512
#define NEGF (-1.0e30f)

typedef float  f32x4 __attribute__((ext_vector_type(4)));
typedef short  s16x8 __attribute__((ext_vector_type(8)));
typedef short  s16x4 __attribute__((ext_vector_type(4)));

// ---- workspace byte offsets ----
#define OFF_QB    ((size_t)0)            // ushort q_bf16 [1024][8192]
#define OFF_WQBT  ((size_t)16777216)     // ushort wq_b^T bf16 [8192][1536]
#define OFF_QRB   ((size_t)41943040)     // ushort qr bf16 [1024][1536]
#define OFF_KPART ((size_t)45088768)     // float kpart [8][1024][192]
#define OFF_KKB   ((size_t)51380224)     // ushort k bf16 [1024][128]
#define OFF_WC    ((size_t)51642368)     // float wc [1024][64]
#define OFF_TRIG  ((size_t)51904512)     // float2 trig [1024][32]
#define OFF_HB    ((size_t)52166656)     // ushort hidden bf16 [1024][7168]
#define OFF_WKPT  ((size_t)66846720)     // ushort [wk|wp]^T bf16 [192][7168]

__device__ __forceinline__ unsigned short f2bf(float x) {
  unsigned int u = __builtin_bit_cast(unsigned int, x);
  u = (u + 0x7FFFu + ((u >> 16) & 1u)) >> 16;
  return (unsigned short)u;
}

__device__ __forceinline__ s16x8 ld_frag(const unsigned short* p) {
  s16x4 lo = *(const s16x4*)p;
  s16x4 hi = *(const s16x4*)(p + 16);
  s16x8 r = { lo[0], lo[1], lo[2], lo[3], hi[0], hi[1], hi[2], hi[3] };
  return r;
}

__device__ __forceinline__ void cp16(unsigned short* dst, const unsigned short* src) {
  s16x8 v = *(const s16x8*)src;            // 16B global load
  s16x4 lo = { v[0], v[1], v[2], v[3] };
  s16x4 hi = { v[4], v[5], v[6], v[7] };
  *(s16x4*)dst = lo;                        // two 8B LDS stores (rows 8B-aligned)
  *(s16x4*)(dst + 4) = hi;
}

// key = (~ascmap(val) << 32) | idx  -> ascending u64 sort == desc val, asc idx
__device__ __forceinline__ unsigned long long packkey(float v, int idx) {
  unsigned int u = __builtin_bit_cast(unsigned int, v);
  unsigned int m = (u & 0x80000000u) ? ~u : (u | 0x80000000u);
  return ((unsigned long long)(~m) << 32) | (unsigned int)idx;
}
__device__ __forceinline__ float unpackval(unsigned long long k) {
  unsigned int m = ~(unsigned int)(k >> 32);
  unsigned int u = (m & 0x80000000u) ? (m ^ 0x80000000u) : ~m;
  return __builtin_bit_cast(float, u);
}

// ---------------- trig table: float2(cos,sin) at [t*32+i] ----------------
__global__ void k_trig(const int* __restrict__ pos, float2* __restrict__ trig) {
  int t = blockIdx.x, i = threadIdx.x;   // 32 threads
  double inv = pow(10000.0, -(double)i / 32.0);
  double ang = (double)pos[t] * inv;
  trig[t*32 + i] = make_float2((float)cos(ang), (float)sin(ang));
}

// ---------------- fp32 -> bf16 (n divisible by 1024) ----------------
__global__ void k_cvt(const float* __restrict__ in, unsigned short* __restrict__ out) {
  int i = (blockIdx.x*256 + threadIdx.x)*4;
  float4 v = *(const float4*)(in + i);
  s16x4 o = { (short)f2bf(v.x), (short)f2bf(v.y), (short)f2bf(v.z), (short)f2bf(v.w) };
  *(s16x4*)(out + i) = o;
}

// ---------------- wq_b [1536][8192] fp32 -> transposed bf16 [8192][1536] ----------------
__global__ __launch_bounds__(256) void k_trcvt(const float* __restrict__ in,
                                               unsigned short* __restrict__ outT) {
  __shared__ float tileS[64][65];
  int n0 = blockIdx.x*64, k0 = blockIdx.y*64;
  int tid = threadIdx.x;
  for (int c = tid; c < 1024; c += 256) {           // 64k x 64n floats
    int r = c >> 4, c4 = (c & 15)*4;
    float4 v = *(const float4*)(in + (size_t)(k0+r)*NQ + n0 + c4);
    tileS[r][c4] = v.x; tileS[r][c4+1] = v.y; tileS[r][c4+2] = v.z; tileS[r][c4+3] = v.w;
  }
  __syncthreads();
  for (int c = tid; c < 512; c += 256) {            // 64n rows x 8-chunks of k
    int rn = c >> 3, c8 = (c & 7)*8;
    s16x8 v;
    #pragma unroll
    for (int u = 0; u < 8; ++u) v[u] = (short)f2bf(tileS[c8+u][rn]);
    *(s16x8*)(outT + (size_t)(n0+rn)*QL + k0 + c8) = v;
  }
}

// ---------------- wk [7168][128] + wp [7168][64] -> [192][7168] bf16 ----------------
__global__ __launch_bounds__(256) void k_trkw(const float* __restrict__ wk,
                                              const float* __restrict__ wp,
                                              unsigned short* __restrict__ wkpT) {
  __shared__ float tileS[64][65];
  int bx = blockIdx.x;                // 0,1 -> wk col-tiles; 2 -> wp
  int k0 = blockIdx.y*64;
  int tid = threadIdx.x;
  const float* src; int stride, c0;
  if (bx < 2) { src = wk; stride = DD; c0 = bx*64; }
  else        { src = wp; stride = NH; c0 = 0; }
  for (int c = tid; c < 1024; c += 256) {
    int r = c >> 4, c4 = (c & 15)*4;
    float4 v = *(const float4*)(src + (size_t)(k0+r)*stride + c0 + c4);
    tileS[r][c4] = v.x; tileS[r][c4+1] = v.y; tileS[r][c4+2] = v.z; tileS[r][c4+3] = v.w;
  }
  __syncthreads();
  int rowOff = bx*64;
  for (int c = tid; c < 512; c += 256) {
    int rn = c >> 3, c8 = (c & 7)*8;
    s16x8 v;
    #pragma unroll
    for (int u = 0; u < 8; ++u) v[u] = (short)f2bf(tileS[c8+u][rn]);
    *(s16x8*)(wkpT + (size_t)(rowOff+rn)*HID + k0 + c8) = v;
  }
}

// ---------------- q = qr @ wq_b via bf16 MFMA, fused RoPE, bf16 out ----------------
__global__ __launch_bounds__(256) void k_gemm_q(const unsigned short* __restrict__ qrb,
                                                const unsigned short* __restrict__ wqbt,
                                                const float2* __restrict__ trig,
                                                unsigned short* __restrict__ qb) {
  __shared__ unsigned short As[128*68];   // A[m][k] pad4
  __shared__ unsigned short Bs[128*68];   // B^T[n][k] pad4
  int tid = threadIdx.x;
  int w = tid >> 6, wr = w >> 1, wc = w & 1, l = tid & 63, lg = l >> 4, lm = l & 15;
  int m0 = blockIdx.y*128, n0 = blockIdx.x*128;
  f32x4 acc[4][4] = {};   // [m-tile][n-tile]
  for (int k0 = 0; k0 < QL; k0 += 64) {
    __syncthreads();
    for (int c = tid; c < 2048; c += 256) {    // 256 rows (128 A + 128 B) x 8 chunks
      int row = c >> 3, col8 = (c & 7)*8;
      if (row < 128)
        cp16(&As[row*68 + col8], qrb  + (size_t)(m0+row)*QL + k0 + col8);
      else
        cp16(&Bs[(row-128)*68 + col8], wqbt + (size_t)(n0+row-128)*QL + k0 + col8);
    }
    __syncthreads();
    #pragma unroll
    for (int kk = 0; kk < 2; ++kk) {
      int kb = kk*32 + 4*lg;
      s16x8 af[4], bfr[4];
      #pragma unroll
      for (int i = 0; i < 4; ++i) af[i] = ld_frag(&As[(wr*64 + i*16 + lm)*68 + kb]);
      #pragma unroll
      for (int j = 0; j < 4; ++j) bfr[j] = ld_frag(&Bs[(wc*64 + j*16 + lm)*68 + kb]);
      #pragma unroll
      for (int i = 0; i < 4; ++i)
        #pragma unroll
        for (int j = 0; j < 4; ++j)
          acc[i][j] = __builtin_amdgcn_mfma_f32_16x16x32_bf16(af[i], bfr[j], acc[i][j], 0, 0, 0);
    }
  }
  #pragma unroll
  for (int i = 0; i < 4; ++i) {
    int trow = m0 + wr*64 + i*16 + lg*4;
    if (wc == 0) {
      #pragma unroll
      for (int r = 0; r < 4; ++r) {
        int t = trow + r;
        #pragma unroll
        for (int jj = 0; jj < 2; ++jj) {
          int idx = jj*16 + lm;
          float2 cs = trig[t*32 + idx];
          float x1 = acc[i][jj][r], x2 = acc[i][jj+2][r];
          acc[i][jj][r]   = x1*cs.x - x2*cs.y;
          acc[i][jj+2][r] = x2*cs.x + x1*cs.y;
        }
      }
    }
    #pragma unroll
    for (int j = 0; j < 4; ++j)
      #pragma unroll
      for (int r = 0; r < 4; ++r)
        qb[(size_t)(trow + r)*NQ + n0 + wc*64 + j*16 + lm] = f2bf(acc[i][j][r]);
  }
}

// ---------------- fused k + w_proj GEMM via bf16 MFMA, split-K 8 ----------------
__global__ __launch_bounds__(256) void k_kw_mfma(const unsigned short* __restrict__ hb,
                                                 const unsigned short* __restrict__ wkpT,
                                                 float* __restrict__ kpart) {
  __shared__ unsigned short As[32*68];
  __shared__ unsigned short Bs[192*68];
  int tid = threadIdx.x;
  int w = tid >> 6, l = tid & 63, lg = l >> 4, lm = l & 15;
  int ks = blockIdx.x, m0 = blockIdx.y*32;
  int kbase = ks*896;
  f32x4 acc[2][3] = {};
  for (int k0 = 0; k0 < 896; k0 += 64) {
    __syncthreads();
    for (int c = tid; c < 1792; c += 256) {     // 224 rows x 8 chunks of 8 ushorts
      int row = c >> 3, col8 = (c & 7)*8;
      if (row < 32)
        cp16(&As[row*68 + col8], hb + (size_t)(m0+row)*HID + kbase + k0 + col8);
      else
        cp16(&Bs[(row-32)*68 + col8], wkpT + (size_t)(row-32)*HID + kbase + k0 + col8);
    }
    __syncthreads();
    #pragma unroll
    for (int kk = 0; kk < 2; ++kk) {
      int kb = kk*32 + 4*lg;
      s16x8 af[2], bfr[3];
      #pragma unroll
      for (int i = 0; i < 2; ++i) af[i] = ld_frag(&As[(i*16 + lm)*68 + kb]);
      #pragma unroll
      for (int j = 0; j < 3; ++j) bfr[j] = ld_frag(&Bs[(w*48 + j*16 + lm)*68 + kb]);
      #pragma unroll
      for (int i = 0; i < 2; ++i)
        #pragma unroll
        for (int j = 0; j < 3; ++j)
          acc[i][j] = __builtin_amdgcn_mfma_f32_16x16x32_bf16(af[i], bfr[j], acc[i][j], 0, 0, 0);
    }
  }
  #pragma unroll
  for (int i = 0; i < 2; ++i)
    #pragma unroll
    for (int j = 0; j < 3; ++j)
      #pragma unroll
      for (int r = 0; r < 4; ++r) {
        int row = m0 + i*16 + lg*4 + r, col = w*48 + j*16 + lm;
        kpart[(size_t)ks*TT*192 + (size_t)row*192 + col] = acc[i][j][r];
      }
}

// ---------------- wc[t,h] ----------------
__global__ void k_post_w(const float* __restrict__ kpart,
                         const float* __restrict__ bp,
                         float* __restrict__ wcq) {
  int g = blockIdx.x*256 + threadIdx.x;   // 65536
  int t = g >> 6, h = g & 63;
  float s = 0.f;
  for (int ks = 0; ks < 8; ++ks)
    s += kpart[(size_t)ks*TT*192 + (size_t)t*192 + 128 + h];
  s = (s + bp[h]) * 0.08838834764831845f;  // 128^-0.5
  wcq[t*64 + h] = s * 0.125f;              // 64^-0.5
}

// ---------------- k partials -> LN -> RoPE -> bf16 ----------------
__global__ __launch_bounds__(128) void k_post_k(const float* __restrict__ kpart,
                                                const float* __restrict__ kg,
                                                const float* __restrict__ kb,
                                                const float2* __restrict__ trig,
                                                unsigned short* __restrict__ kkb) {
  __shared__ float red[128];
  __shared__ float row[128];
  int t = blockIdx.x, d = threadIdx.x;
  float v = 0.f;
  for (int ks = 0; ks < 8; ++ks)
    v += kpart[(size_t)ks*TT*192 + (size_t)t*192 + d];
  red[d] = v; __syncthreads();
  for (int off = 64; off; off >>= 1) { if (d < off) red[d] += red[d+off]; __syncthreads(); }
  float mu = red[0] * (1.f/128.f); __syncthreads();
  float diff = v - mu;
  red[d] = diff*diff; __syncthreads();
  for (int off = 64; off; off >>= 1) { if (d < off) red[d] += red[d+off]; __syncthreads(); }
  float var = red[0] * (1.f/128.f);
  float rsq = 1.f / sqrtf(var + 1e-6f);
  float kn = (v - mu) * rsq * kg[d] + kb[d];
  row[d] = kn; __syncthreads();
  float outv;
  if (d < 32) {
    float2 cs = trig[t*32 + d];
    outv = row[d]*cs.x - row[d+32]*cs.y;
  } else if (d < 64) {
    float2 cs = trig[t*32 + d - 32];
    outv = row[d]*cs.x + row[d-32]*cs.y;
  } else outv = kn;
  kkb[(size_t)t*DD + d] = f2bf(outv);
}

// ---------------- scores (bf16 MFMA) + mask + packed-u64 bitonic top-512 ----------------
__global__ __launch_bounds__(512) void k_scores(const unsigned short* __restrict__ qb,
                                                const unsigned short* __restrict__ kkb,
                                                const float* __restrict__ wcq,
                                                const int* __restrict__ pos,
                                                float* __restrict__ out) {
  __shared__ unsigned short Qs[64*132];    // Q[h][d] pad4  (16.9 KB)
  __shared__ unsigned short Ks[128*132];   // K[s][d] pad4  (33.8 KB)
  __shared__ unsigned long long keys[1024];// packed (val,idx) (8 KB)
  int tid = threadIdx.x;
  int bid = blockIdx.x;
  int t = (bid & 1) ? (1023 - (bid >> 1)) : (bid >> 1);   // load-balance heavy/light rows
  int w = tid >> 6, l = tid & 63, lg = l >> 4, lm = l & 15;
  for (int e = tid; e < 1024; e += 512) keys[e] = packkey(NEGF, e);
  for (int c = tid; c < 1024; c += 512) {          // stage Q: 64h x 16 chunks
    int h = c >> 4, d8 = (c & 15)*8;
    cp16(&Qs[h*132 + d8], qb + (size_t)t*NQ + h*DD + d8);
  }
  float wreg[4];
  #pragma unroll
  for (int j = 0; j < 4; ++j) wreg[j] = wcq[t*64 + j*16 + lm];
  int post = pos[t];
  int niter = (t >> 7) + 1;
  for (int it = 0; it < niter; ++it) {
    int s0 = it << 7;
    __syncthreads();
    for (int c = tid; c < 2048; c += 512) {        // stage K: 128s x 16 chunks
      int s = c >> 4, d8 = (c & 15)*8;
      cp16(&Ks[s*132 + d8], kkb + (size_t)(s0+s)*DD + d8);
    }
    __syncthreads();
    f32x4 acc[4] = {};
    #pragma unroll
    for (int ksb = 0; ksb < 4; ++ksb) {            // d in steps of 32
      int kbd = ksb*32 + 4*lg;
      s16x8 af = ld_frag(&Ks[(w*16 + lm)*132 + kbd]);
      #pragma unroll
      for (int j = 0; j < 4; ++j) {
        s16x8 bfr = ld_frag(&Qs[(j*16 + lm)*132 + kbd]);
        acc[j] = __builtin_amdgcn_mfma_f32_16x16x32_bf16(af, bfr, acc[j], 0, 0, 0);
      }
    }
    #pragma unroll
    for (int r = 0; r < 4; ++r) {
      float p = 0.f;
      #pragma unroll
      for (int j = 0; j < 4; ++j) p += fmaxf(acc[j][r], 0.f) * wreg[j];
      p += __shfl_xor(p, 1); p += __shfl_xor(p, 2);
      p += __shfl_xor(p, 4); p += __shfl_xor(p, 8);
      if (lm == 0) {
        int s = s0 + w*16 + lg*4 + r;
        keys[s] = packkey((post >= pos[s]) ? p : NEGF, s);
      }
    }
  }
  __syncthreads();
  // bitonic: stages kk=2..512 full-width (45 passes, 1 comparator/thread)
  for (int kk2 = 2; kk2 <= 512; kk2 <<= 1) {
    for (int j = kk2 >> 1; j > 0; j >>= 1) {
      int i = ((tid & ~(j-1)) << 1) | (tid & (j-1));
      int lp = i | j;
      unsigned long long a = keys[i], b = keys[lp];
      bool up = ((i & kk2) == 0);
      if (up ? (a > b) : (a < b)) { keys[i] = b; keys[lp] = a; }
      __syncthreads();
    }
  }
  // final merge kk=1024: j=512 splits off top-512 (smallest keys) into lower half
  {
    unsigned long long a = keys[tid], b = keys[tid | 512];
    if (a > b) { keys[tid] = b; keys[tid | 512] = a; }
    __syncthreads();
  }
  // sort only the lower 512 (bitonic merge, 9 half-width passes)
  for (int j = 256; j > 0; j >>= 1) {
    if (tid < 256) {
      int i = ((tid & ~(j-1)) << 1) | (tid & (j-1));
      int lp = i | j;
      unsigned long long a = keys[i], b = keys[lp];
      if (a > b) { keys[i] = b; keys[lp] = a; }
    }
    __syncthreads();
  }
  {
    unsigned long long k = keys[tid];
    float v = unpackval(k);
    out[(size_t)t*TOPK + tid] = v;
    out[(size_t)TT*TOPK + (size_t)t*TOPK + tid] =
        (v > 0.5f*NEGF) ? (float)(unsigned int)(k & 0xFFFFFFFFu) : -1.0f;
  }
}

extern "C" void kernel_launch(void* const* d_in, const int* in_sizes, int n_in,
                              void* d_out, int out_size, void* d_ws, size_t ws_size,
                              hipStream_t stream) {
  const float* hidden = (const float*)d_in[0];
  const float* qr     = (const float*)d_in[1];
  const float* wqb    = (const float*)d_in[2];
  const float* wk     = (const float*)d_in[3];
  const float* kg     = (const float*)d_in[4];
  const float* kb     = (const float*)d_in[5];
  const float* wp     = (const float*)d_in[6];
  const float* bp     = (const float*)d_in[7];
  const int*   pos    = (const int*)d_in[8];
  float* out = (float*)d_out;

  char* W = (char*)d_ws;
  unsigned short* qbuf  = (unsigned short*)(W + OFF_QB);
  unsigned short* wqbt  = (unsigned short*)(W + OFF_WQBT);
  unsigned short* qrb   = (unsigned short*)(W + OFF_QRB);
  float*          kpart = (float*)(W + OFF_KPART);
  unsigned short* kkbuf = (unsigned short*)(W + OFF_KKB);
  float*          wcq   = (float*)(W + OFF_WC);
  float2*         trig  = (float2*)(W + OFF_TRIG);
  unsigned short* hb    = (unsigned short*)(W + OFF_HB);
  unsigned short* wkpT  = (unsigned short*)(W + OFF_WKPT);

  k_trig   <<<TT, 32, 0, stream>>>(pos, trig);
  k_cvt    <<<(TT*QL)/1024, 256, 0, stream>>>(qr, qrb);
  k_cvt    <<<(TT*HID)/1024, 256, 0, stream>>>(hidden, hb);
  k_trcvt  <<<dim3(NQ/64, QL/64), 256, 0, stream>>>(wqb, wqbt);
  k_trkw   <<<dim3(3, HID/64), 256, 0, stream>>>(wk, wp, wkpT);
  k_gemm_q <<<dim3(NQ/128, TT/128), 256, 0, stream>>>(qrb, wqbt, trig, qbuf);
  k_kw_mfma<<<dim3(8, TT/32), 256, 0, stream>>>(hb, wkpT, kpart);
  k_post_w <<<(TT*NH)/256, 256, 0, stream>>>(kpart, bp, wcq);
  k_post_k <<<TT, 128, 0, stream>>>(kpart, kg, kb, trig, kkbuf);
  k_scores <<<TT, 512, 0, stream>>>(qbuf, kkbuf, wcq, pos, out);
}

// Round 7
// 295.975 us; speedup vs baseline: 4.9865x; 1.1981x over previous
//
#include <hip/hip_runtime.h>
#include <math.h>

#define TT 1024
#define HID 7168
#define QL 1536
#define NH 64
#define DD 128
#define NQ 8192
#define TOPK 512
#define NEGF (-1.0e30f)

typedef float  f32x4 __attribute__((ext_vector_type(4)));
typedef short  s16x8 __attribute__((ext_vector_type(8)));
typedef short  s16x4 __attribute__((ext_vector_type(4)));

// ---- workspace byte offsets ----
#define OFF_QB    ((size_t)0)            // ushort q_bf16 [1024][8192]
#define OFF_WQBT  ((size_t)16777216)     // ushort wq_b^T bf16 [8192][1536] (frag-permuted k)
#define OFF_QRB   ((size_t)41943040)     // ushort qr bf16 [1024][1536]     (frag-permuted k)
#define OFF_KPART ((size_t)45088768)     // float kpart [8][1024][192]
#define OFF_KKB   ((size_t)51380224)     // ushort k bf16 [1024][128]
#define OFF_WC    ((size_t)51642368)     // float wc [1024][64]
#define OFF_TRIG  ((size_t)51904512)     // float2 trig [1024][32]
#define OFF_HB    ((size_t)52166656)     // ushort hidden bf16 [1024][7168] (linear)
#define OFF_WKPT  ((size_t)66846720)     // ushort [wk|wp]^T bf16 [192][7168] (linear)

__device__ __forceinline__ unsigned short f2bf(float x) {
  unsigned int u = __builtin_bit_cast(unsigned int, x);
  u = (u + 0x7FFFu + ((u >> 16) & 1u)) >> 16;
  return (unsigned short)u;
}

__device__ __forceinline__ s16x8 ld_frag(const unsigned short* p) {
  s16x4 lo = *(const s16x4*)p;
  s16x4 hi = *(const s16x4*)(p + 16);
  s16x8 r = { lo[0], lo[1], lo[2], lo[3], hi[0], hi[1], hi[2], hi[3] };
  return r;
}

__device__ __forceinline__ void cp16(unsigned short* dst, const unsigned short* src) {
  s16x8 v = *(const s16x8*)src;
  s16x4 lo = { v[0], v[1], v[2], v[3] };
  s16x4 hi = { v[4], v[5], v[6], v[7] };
  *(s16x4*)dst = lo;
  *(s16x4*)(dst + 4) = hi;
}

// frag-permutation: logical 4-group g (k/4) -> physical 4-group within row.
// within each 64-elem k-block: phys p = kk*32+lg*8+pc*4+e holds logical k = kk*32+lg*4+pc*16+e
__device__ __forceinline__ int perm4(int g) {
  int k64 = g >> 4, r = g & 15;
  int kk = r >> 3, pc = (r >> 2) & 1, lg = r & 3;
  return k64*16 + kk*8 + lg*2 + pc;
}

// key = (~ascmap(val) << 32) | idx  -> ascending u64 sort == desc val, asc idx
__device__ __forceinline__ unsigned long long packkey(float v, int idx) {
  unsigned int u = __builtin_bit_cast(unsigned int, v);
  unsigned int m = (u & 0x80000000u) ? ~u : (u | 0x80000000u);
  return ((unsigned long long)(~m) << 32) | (unsigned int)idx;
}
__device__ __forceinline__ float unpackval(unsigned long long k) {
  unsigned int m = ~(unsigned int)(k >> 32);
  unsigned int u = (m & 0x80000000u) ? (m ^ 0x80000000u) : ~m;
  return __builtin_bit_cast(float, u);
}

// ---------------- trig table ----------------
__global__ void k_trig(const int* __restrict__ pos, float2* __restrict__ trig) {
  int t = blockIdx.x, i = threadIdx.x;
  double inv = pow(10000.0, -(double)i / 32.0);
  double ang = (double)pos[t] * inv;
  trig[t*32 + i] = make_float2((float)cos(ang), (float)sin(ang));
}

// ---------------- fp32 -> bf16 linear (hidden) ----------------
__global__ void k_cvt(const float* __restrict__ in, unsigned short* __restrict__ out) {
  int i = (blockIdx.x*256 + threadIdx.x)*4;
  float4 v = *(const float4*)(in + i);
  s16x4 o = { (short)f2bf(v.x), (short)f2bf(v.y), (short)f2bf(v.z), (short)f2bf(v.w) };
  *(s16x4*)(out + i) = o;
}

// ---------------- qr fp32 -> bf16, frag-permuted k (row len QL) ----------------
__global__ void k_cvtp(const float* __restrict__ in, unsigned short* __restrict__ out) {
  int idx = blockIdx.x*256 + threadIdx.x;     // logical 4-group, total TT*QL/4
  int row = idx / (QL/4);
  int g   = idx - row*(QL/4);
  float4 v = *(const float4*)(in + (size_t)idx*4);
  s16x4 o = { (short)f2bf(v.x), (short)f2bf(v.y), (short)f2bf(v.z), (short)f2bf(v.w) };
  *(s16x4*)(out + (size_t)row*QL + perm4(g)*4) = o;
}

// ---------------- wq_b [1536][8192] -> transposed bf16 [8192][1536], frag-permuted k ----------------
__global__ __launch_bounds__(256) void k_trcvt(const float* __restrict__ in,
                                               unsigned short* __restrict__ outT) {
  __shared__ float tileS[64][65];
  int n0 = blockIdx.x*64, k0 = blockIdx.y*64;
  int tid = threadIdx.x;
  for (int c = tid; c < 1024; c += 256) {
    int r = c >> 4, c4 = (c & 15)*4;
    float4 v = *(const float4*)(in + (size_t)(k0+r)*NQ + n0 + c4);
    tileS[r][c4] = v.x; tileS[r][c4+1] = v.y; tileS[r][c4+2] = v.z; tileS[r][c4+3] = v.w;
  }
  __syncthreads();
  for (int c = tid; c < 512; c += 256) {
    int rn = c >> 3, c8 = (c & 7)*8;           // logical k chunk of 8 within block
    s16x4 a, b;
    #pragma unroll
    for (int u = 0; u < 4; ++u) a[u] = (short)f2bf(tileS[c8+u][rn]);
    #pragma unroll
    for (int u = 0; u < 4; ++u) b[u] = (short)f2bf(tileS[c8+4+u][rn]);
    int gA = (k0 + c8) >> 2;
    *(s16x4*)(outT + (size_t)(n0+rn)*QL + perm4(gA)*4)   = a;
    *(s16x4*)(outT + (size_t)(n0+rn)*QL + perm4(gA+1)*4) = b;
  }
}

// ---------------- wk + wp -> [192][7168] bf16 linear ----------------
__global__ __launch_bounds__(256) void k_trkw(const float* __restrict__ wk,
                                              const float* __restrict__ wp,
                                              unsigned short* __restrict__ wkpT) {
  __shared__ float tileS[64][65];
  int bx = blockIdx.x;
  int k0 = blockIdx.y*64;
  int tid = threadIdx.x;
  const float* src; int stride, c0;
  if (bx < 2) { src = wk; stride = DD; c0 = bx*64; }
  else        { src = wp; stride = NH; c0 = 0; }
  for (int c = tid; c < 1024; c += 256) {
    int r = c >> 4, c4 = (c & 15)*4;
    float4 v = *(const float4*)(src + (size_t)(k0+r)*stride + c0 + c4);
    tileS[r][c4] = v.x; tileS[r][c4+1] = v.y; tileS[r][c4+2] = v.z; tileS[r][c4+3] = v.w;
  }
  __syncthreads();
  int rowOff = bx*64;
  for (int c = tid; c < 512; c += 256) {
    int rn = c >> 3, c8 = (c & 7)*8;
    s16x8 v;
    #pragma unroll
    for (int u = 0; u < 8; ++u) v[u] = (short)f2bf(tileS[c8+u][rn]);
    *(s16x8*)(wkpT + (size_t)(rowOff+rn)*HID + k0 + c8) = v;
  }
}

// ---------------- q = qr @ wq_b : m97-style MFMA GEMM, gload_lds + swizzled frag layout ----------------
__global__ __launch_bounds__(256) void k_gemm_q(const unsigned short* __restrict__ qrb,
                                                const unsigned short* __restrict__ wqbt,
                                                const float2* __restrict__ trig,
                                                unsigned short* __restrict__ qb) {
  __shared__ __align__(16) unsigned short As[128*64];   // linear, frag-order, swizzled chunks
  __shared__ __align__(16) unsigned short Bs[128*64];
  int tid = threadIdx.x;
  int w = tid >> 6, wr = w >> 1, wc = w & 1, l = tid & 63, lg = l >> 4, lm = l & 15;
  int m0 = blockIdx.y*128, n0 = blockIdx.x*128;
  f32x4 acc[4][4] = {};
  for (int k0 = 0; k0 < QL; k0 += 64) {
    __syncthreads();
    #pragma unroll
    for (int u = 0; u < 4; ++u) {               // A: 128 rows x 64 k (frag-permuted)
      int c = tid + 256*u;
      int row = c >> 3, cp = c & 7;
      int srcc = (cp ^ (row & 7)) * 8;          // inverse-swizzled global chunk
      __builtin_amdgcn_global_load_lds(
        (const __attribute__((address_space(1))) unsigned int*)(qrb + (size_t)(m0+row)*QL + k0 + srcc),
        (__attribute__((address_space(3))) unsigned int*)(As + (size_t)c*8), 16, 0, 0);
    }
    #pragma unroll
    for (int u = 0; u < 4; ++u) {               // B
      int c = tid + 256*u;
      int row = c >> 3, cp = c & 7;
      int srcc = (cp ^ (row & 7)) * 8;
      __builtin_amdgcn_global_load_lds(
        (const __attribute__((address_space(1))) unsigned int*)(wqbt + (size_t)(n0+row)*QL + k0 + srcc),
        (__attribute__((address_space(3))) unsigned int*)(Bs + (size_t)c*8), 16, 0, 0);
    }
    __syncthreads();                            // implies vmcnt(0) drain
    #pragma unroll
    for (int kk = 0; kk < 2; ++kk) {
      s16x8 af[4], bfr[4];
      #pragma unroll
      for (int i = 0; i < 4; ++i) {
        int row = wr*64 + i*16 + lm;
        int ch = (kk*4 + lg) ^ (row & 7);
        af[i] = *(const s16x8*)(As + row*64 + ch*8);   // one ds_read_b128, conflict-free
      }
      #pragma unroll
      for (int j = 0; j < 4; ++j) {
        int row = wc*64 + j*16 + lm;
        int ch = (kk*4 + lg) ^ (row & 7);
        bfr[j] = *(const s16x8*)(Bs + row*64 + ch*8);
      }
      #pragma unroll
      for (int i = 0; i < 4; ++i)
        #pragma unroll
        for (int j = 0; j < 4; ++j)
          acc[i][j] = __builtin_amdgcn_mfma_f32_16x16x32_bf16(af[i], bfr[j], acc[i][j], 0, 0, 0);
    }
  }
  #pragma unroll
  for (int i = 0; i < 4; ++i) {
    int trow = m0 + wr*64 + i*16 + lg*4;
    if (wc == 0) {
      #pragma unroll
      for (int r = 0; r < 4; ++r) {
        int t = trow + r;
        #pragma unroll
        for (int jj = 0; jj < 2; ++jj) {
          int idx = jj*16 + lm;
          float2 cs = trig[t*32 + idx];
          float x1 = acc[i][jj][r], x2 = acc[i][jj+2][r];
          acc[i][jj][r]   = x1*cs.x - x2*cs.y;
          acc[i][jj+2][r] = x2*cs.x + x1*cs.y;
        }
      }
    }
    #pragma unroll
    for (int j = 0; j < 4; ++j)
      #pragma unroll
      for (int r = 0; r < 4; ++r)
        qb[(size_t)(trow + r)*NQ + n0 + wc*64 + j*16 + lm] = f2bf(acc[i][j][r]);
  }
}

// ---------------- fused k + w_proj GEMM via bf16 MFMA, split-K 8 (unchanged) ----------------
__global__ __launch_bounds__(256) void k_kw_mfma(const unsigned short* __restrict__ hb,
                                                 const unsigned short* __restrict__ wkpT,
                                                 float* __restrict__ kpart) {
  __shared__ unsigned short As[32*68];
  __shared__ unsigned short Bs[192*68];
  int tid = threadIdx.x;
  int w = tid >> 6, l = tid & 63, lg = l >> 4, lm = l & 15;
  int ks = blockIdx.x, m0 = blockIdx.y*32;
  int kbase = ks*896;
  f32x4 acc[2][3] = {};
  for (int k0 = 0; k0 < 896; k0 += 64) {
    __syncthreads();
    for (int c = tid; c < 1792; c += 256) {
      int row = c >> 3, col8 = (c & 7)*8;
      if (row < 32)
        cp16(&As[row*68 + col8], hb + (size_t)(m0+row)*HID + kbase + k0 + col8);
      else
        cp16(&Bs[(row-32)*68 + col8], wkpT + (size_t)(row-32)*HID + kbase + k0 + col8);
    }
    __syncthreads();
    #pragma unroll
    for (int kk = 0; kk < 2; ++kk) {
      int kb = kk*32 + 4*lg;
      s16x8 af[2], bfr[3];
      #pragma unroll
      for (int i = 0; i < 2; ++i) af[i] = ld_frag(&As[(i*16 + lm)*68 + kb]);
      #pragma unroll
      for (int j = 0; j < 3; ++j) bfr[j] = ld_frag(&Bs[(w*48 + j*16 + lm)*68 + kb]);
      #pragma unroll
      for (int i = 0; i < 2; ++i)
        #pragma unroll
        for (int j = 0; j < 3; ++j)
          acc[i][j] = __builtin_amdgcn_mfma_f32_16x16x32_bf16(af[i], bfr[j], acc[i][j], 0, 0, 0);
    }
  }
  #pragma unroll
  for (int i = 0; i < 2; ++i)
    #pragma unroll
    for (int j = 0; j < 3; ++j)
      #pragma unroll
      for (int r = 0; r < 4; ++r) {
        int row = m0 + i*16 + lg*4 + r, col = w*48 + j*16 + lm;
        kpart[(size_t)ks*TT*192 + (size_t)row*192 + col] = acc[i][j][r];
      }
}

// ---------------- wc[t,h] ----------------
__global__ void k_post_w(const float* __restrict__ kpart,
                         const float* __restrict__ bp,
                         float* __restrict__ wcq) {
  int g = blockIdx.x*256 + threadIdx.x;
  int t = g >> 6, h = g & 63;
  float s = 0.f;
  for (int ks = 0; ks < 8; ++ks)
    s += kpart[(size_t)ks*TT*192 + (size_t)t*192 + 128 + h];
  s = (s + bp[h]) * 0.08838834764831845f;
  wcq[t*64 + h] = s * 0.125f;
}

// ---------------- k partials -> LN -> RoPE -> bf16 ----------------
__global__ __launch_bounds__(128) void k_post_k(const float* __restrict__ kpart,
                                                const float* __restrict__ kg,
                                                const float* __restrict__ kb,
                                                const float2* __restrict__ trig,
                                                unsigned short* __restrict__ kkb) {
  __shared__ float red[128];
  __shared__ float row[128];
  int t = blockIdx.x, d = threadIdx.x;
  float v = 0.f;
  for (int ks = 0; ks < 8; ++ks)
    v += kpart[(size_t)ks*TT*192 + (size_t)t*192 + d];
  red[d] = v; __syncthreads();
  for (int off = 64; off; off >>= 1) { if (d < off) red[d] += red[d+off]; __syncthreads(); }
  float mu = red[0] * (1.f/128.f); __syncthreads();
  float diff = v - mu;
  red[d] = diff*diff; __syncthreads();
  for (int off = 64; off; off >>= 1) { if (d < off) red[d] += red[d+off]; __syncthreads(); }
  float var = red[0] * (1.f/128.f);
  float rsq = 1.f / sqrtf(var + 1e-6f);
  float kn = (v - mu) * rsq * kg[d] + kb[d];
  row[d] = kn; __syncthreads();
  float outv;
  if (d < 32) {
    float2 cs = trig[t*32 + d];
    outv = row[d]*cs.x - row[d+32]*cs.y;
  } else if (d < 64) {
    float2 cs = trig[t*32 + d - 32];
    outv = row[d]*cs.x + row[d-32]*cs.y;
  } else outv = kn;
  kkb[(size_t)t*DD + d] = f2bf(outv);
}

// ---------------- scores (bf16 MFMA) + mask + packed-u64 bitonic top-512 ----------------
__global__ __launch_bounds__(512) void k_scores(const unsigned short* __restrict__ qb,
                                                const unsigned short* __restrict__ kkb,
                                                const float* __restrict__ wcq,
                                                const int* __restrict__ pos,
                                                float* __restrict__ out) {
  __shared__ unsigned short Qs[64*132];
  __shared__ unsigned short Ks[128*132];
  __shared__ unsigned long long keys[1024];
  int tid = threadIdx.x;
  int bid = blockIdx.x;
  int t = (bid & 1) ? (1023 - (bid >> 1)) : (bid >> 1);
  int w = tid >> 6, l = tid & 63, lg = l >> 4, lm = l & 15;
  for (int e = tid; e < 1024; e += 512) keys[e] = packkey(NEGF, e);
  for (int c = tid; c < 1024; c += 512) {
    int h = c >> 4, d8 = (c & 15)*8;
    cp16(&Qs[h*132 + d8], qb + (size_t)t*NQ + h*DD + d8);
  }
  float wreg[4];
  #pragma unroll
  for (int j = 0; j < 4; ++j) wreg[j] = wcq[t*64 + j*16 + lm];
  int post = pos[t];
  int niter = (t >> 7) + 1;
  for (int it = 0; it < niter; ++it) {
    int s0 = it << 7;
    __syncthreads();
    for (int c = tid; c < 2048; c += 512) {
      int s = c >> 4, d8 = (c & 15)*8;
      cp16(&Ks[s*132 + d8], kkb + (size_t)(s0+s)*DD + d8);
    }
    __syncthreads();
    f32x4 acc[4] = {};
    #pragma unroll
    for (int ksb = 0; ksb < 4; ++ksb) {
      int kbd = ksb*32 + 4*lg;
      s16x8 af = ld_frag(&Ks[(w*16 + lm)*132 + kbd]);
      #pragma unroll
      for (int j = 0; j < 4; ++j) {
        s16x8 bfr = ld_frag(&Qs[(j*16 + lm)*132 + kbd]);
        acc[j] = __builtin_amdgcn_mfma_f32_16x16x32_bf16(af, bfr, acc[j], 0, 0, 0);
      }
    }
    #pragma unroll
    for (int r = 0; r < 4; ++r) {
      float p = 0.f;
      #pragma unroll
      for (int j = 0; j < 4; ++j) p += fmaxf(acc[j][r], 0.f) * wreg[j];
      p += __shfl_xor(p, 1); p += __shfl_xor(p, 2);
      p += __shfl_xor(p, 4); p += __shfl_xor(p, 8);
      if (lm == 0) {
        int s = s0 + w*16 + lg*4 + r;
        keys[s] = packkey((post >= pos[s]) ? p : NEGF, s);
      }
    }
  }
  __syncthreads();
  for (int kk2 = 2; kk2 <= 512; kk2 <<= 1) {
    for (int j = kk2 >> 1; j > 0; j >>= 1) {
      int i = ((tid & ~(j-1)) << 1) | (tid & (j-1));
      int lp = i | j;
      unsigned long long a = keys[i], b = keys[lp];
      bool up = ((i & kk2) == 0);
      if (up ? (a > b) : (a < b)) { keys[i] = b; keys[lp] = a; }
      __syncthreads();
    }
  }
  {
    unsigned long long a = keys[tid], b = keys[tid | 512];
    if (a > b) { keys[tid] = b; keys[tid | 512] = a; }
    __syncthreads();
  }
  for (int j = 256; j > 0; j >>= 1) {
    if (tid < 256) {
      int i = ((tid & ~(j-1)) << 1) | (tid & (j-1));
      int lp = i | j;
      unsigned long long a = keys[i], b = keys[lp];
      if (a > b) { keys[i] = b; keys[lp] = a; }
    }
    __syncthreads();
  }
  {
    unsigned long long k = keys[tid];
    float v = unpackval(k);
    out[(size_t)t*TOPK + tid] = v;
    out[(size_t)TT*TOPK + (size_t)t*TOPK + tid] =
        (v > 0.5f*NEGF) ? (float)(unsigned int)(k & 0xFFFFFFFFu) : -1.0f;
  }
}

extern "C" void kernel_launch(void* const* d_in, const int* in_sizes, int n_in,
                              void* d_out, int out_size, void* d_ws, size_t ws_size,
                              hipStream_t stream) {
  const float* hidden = (const float*)d_in[0];
  const float* qr     = (const float*)d_in[1];
  const float* wqb    = (const float*)d_in[2];
  const float* wk     = (const float*)d_in[3];
  const float* kg     = (const float*)d_in[4];
  const float* kb     = (const float*)d_in[5];
  const float* wp     = (const float*)d_in[6];
  const float* bp     = (const float*)d_in[7];
  const int*   pos    = (const int*)d_in[8];
  float* out = (float*)d_out;

  char* W = (char*)d_ws;
  unsigned short* qbuf  = (unsigned short*)(W + OFF_QB);
  unsigned short* wqbt  = (unsigned short*)(W + OFF_WQBT);
  unsigned short* qrb   = (unsigned short*)(W + OFF_QRB);
  float*          kpart = (float*)(W + OFF_KPART);
  unsigned short* kkbuf = (unsigned short*)(W + OFF_KKB);
  float*          wcq   = (float*)(W + OFF_WC);
  float2*         trig  = (float2*)(W + OFF_TRIG);
  unsigned short* hb    = (unsigned short*)(W + OFF_HB);
  unsigned short* wkpT  = (unsigned short*)(W + OFF_WKPT);

  k_trig   <<<TT, 32, 0, stream>>>(pos, trig);
  k_cvtp   <<<(TT*QL/4)/256, 256, 0, stream>>>(qr, qrb);
  k_cvt    <<<(TT*HID)/1024, 256, 0, stream>>>(hidden, hb);
  k_trcvt  <<<dim3(NQ/64, QL/64), 256, 0, stream>>>(wqb, wqbt);
  k_trkw   <<<dim3(3, HID/64), 256, 0, stream>>>(wk, wp, wkpT);
  k_gemm_q <<<dim3(NQ/128, TT/128), 256, 0, stream>>>(qrb, wqbt, trig, qbuf);
  k_kw_mfma<<<dim3(8, TT/32), 256, 0, stream>>>(hb, wkpT, kpart);
  k_post_w <<<(TT*NH)/256, 256, 0, stream>>>(kpart, bp, wcq);
  k_post_k <<<TT, 128, 0, stream>>>(kpart, kg, kb, trig, kkbuf);
  k_scores <<<TT, 512, 0, stream>>>(qbuf, kkbuf, wcq, pos, out);
}

// Round 8
// 285.389 us; speedup vs baseline: 5.1715x; 1.0371x over previous
//
#include <hip/hip_runtime.h>
#include <math.h>

#define TT 1024
#define HID 7168
#define QL 1536
#define NH 64
#define DD 128
#define NQ 8192
#define TOPK 512
#define NEGF (-1.0e30f)

typedef float  f32x4 __attribute__((ext_vector_type(4)));
typedef short  s16x8 __attribute__((ext_vector_type(8)));
typedef short  s16x4 __attribute__((ext_vector_type(4)));

// ---- workspace byte offsets ----
#define OFF_QB    ((size_t)0)            // ushort q_bf16 [1024][8192]
#define OFF_WQBT  ((size_t)16777216)     // ushort wq_b^T bf16 [8192][1536] (frag-permuted k)
#define OFF_QRB   ((size_t)41943040)     // ushort qr bf16 [1024][1536]     (frag-permuted k)
#define OFF_KPART ((size_t)45088768)     // float kpart [8][1024][192]
#define OFF_KKB   ((size_t)51380224)     // ushort k bf16 [1024][128] (frag-permuted d)
#define OFF_WC    ((size_t)51642368)     // float wc [1024][64]
#define OFF_TRIG  ((size_t)51904512)     // float2 trig [1024][32]
#define OFF_HB    ((size_t)52166656)     // ushort hidden bf16 [1024][7168] (linear)
#define OFF_WKPT  ((size_t)66846720)     // ushort [wk|wp]^T bf16 [192][7168] (linear)

__device__ __forceinline__ unsigned short f2bf(float x) {
  unsigned int u = __builtin_bit_cast(unsigned int, x);
  u = (u + 0x7FFFu + ((u >> 16) & 1u)) >> 16;
  return (unsigned short)u;
}

__device__ __forceinline__ s16x8 ld_frag(const unsigned short* p) {
  s16x4 lo = *(const s16x4*)p;
  s16x4 hi = *(const s16x4*)(p + 16);
  s16x8 r = { lo[0], lo[1], lo[2], lo[3], hi[0], hi[1], hi[2], hi[3] };
  return r;
}

__device__ __forceinline__ void cp16(unsigned short* dst, const unsigned short* src) {
  s16x8 v = *(const s16x8*)src;
  s16x4 lo = { v[0], v[1], v[2], v[3] };
  s16x4 hi = { v[4], v[5], v[6], v[7] };
  *(s16x4*)dst = lo;
  *(s16x4*)(dst + 4) = hi;
}

// frag-permutation: logical 4-group g (k/4) -> physical 4-group within row.
__device__ __forceinline__ int perm4(int g) {
  int k64 = g >> 4, r = g & 15;
  int kk = r >> 3, pc = (r >> 2) & 1, lg = r & 3;
  return k64*16 + kk*8 + lg*2 + pc;
}

// key = (~ascmap(val) << 32) | idx  -> ascending u64 sort == desc val, asc idx
__device__ __forceinline__ unsigned long long packkey(float v, int idx) {
  unsigned int u = __builtin_bit_cast(unsigned int, v);
  unsigned int m = (u & 0x80000000u) ? ~u : (u | 0x80000000u);
  return ((unsigned long long)(~m) << 32) | (unsigned int)idx;
}
__device__ __forceinline__ float unpackval(unsigned long long k) {
  unsigned int m = ~(unsigned int)(k >> 32);
  unsigned int u = (m & 0x80000000u) ? (m ^ 0x80000000u) : ~m;
  return __builtin_bit_cast(float, u);
}

__device__ __forceinline__ unsigned long long shfl_xor_u64(unsigned long long v, int m) {
  unsigned int lo = (unsigned int)v, hi = (unsigned int)(v >> 32);
  lo = __shfl_xor(lo, m); hi = __shfl_xor(hi, m);
  return ((unsigned long long)hi << 32) | lo;
}

// ---------------- trig table ----------------
__global__ void k_trig(const int* __restrict__ pos, float2* __restrict__ trig) {
  int t = blockIdx.x, i = threadIdx.x;
  double inv = pow(10000.0, -(double)i / 32.0);
  double ang = (double)pos[t] * inv;
  trig[t*32 + i] = make_float2((float)cos(ang), (float)sin(ang));
}

// ---------------- fp32 -> bf16 linear (hidden) ----------------
__global__ void k_cvt(const float* __restrict__ in, unsigned short* __restrict__ out) {
  int i = (blockIdx.x*256 + threadIdx.x)*4;
  float4 v = *(const float4*)(in + i);
  s16x4 o = { (short)f2bf(v.x), (short)f2bf(v.y), (short)f2bf(v.z), (short)f2bf(v.w) };
  *(s16x4*)(out + i) = o;
}

// ---------------- qr fp32 -> bf16, frag-permuted k ----------------
__global__ void k_cvtp(const float* __restrict__ in, unsigned short* __restrict__ out) {
  int idx = blockIdx.x*256 + threadIdx.x;
  int row = idx / (QL/4);
  int g   = idx - row*(QL/4);
  float4 v = *(const float4*)(in + (size_t)idx*4);
  s16x4 o = { (short)f2bf(v.x), (short)f2bf(v.y), (short)f2bf(v.z), (short)f2bf(v.w) };
  *(s16x4*)(out + (size_t)row*QL + perm4(g)*4) = o;
}

// ---------------- wq_b -> transposed bf16, frag-permuted k ----------------
__global__ __launch_bounds__(256) void k_trcvt(const float* __restrict__ in,
                                               unsigned short* __restrict__ outT) {
  __shared__ float tileS[64][65];
  int n0 = blockIdx.x*64, k0 = blockIdx.y*64;
  int tid = threadIdx.x;
  for (int c = tid; c < 1024; c += 256) {
    int r = c >> 4, c4 = (c & 15)*4;
    float4 v = *(const float4*)(in + (size_t)(k0+r)*NQ + n0 + c4);
    tileS[r][c4] = v.x; tileS[r][c4+1] = v.y; tileS[r][c4+2] = v.z; tileS[r][c4+3] = v.w;
  }
  __syncthreads();
  for (int c = tid; c < 512; c += 256) {
    int rn = c >> 3, c8 = (c & 7)*8;
    s16x4 a, b;
    #pragma unroll
    for (int u = 0; u < 4; ++u) a[u] = (short)f2bf(tileS[c8+u][rn]);
    #pragma unroll
    for (int u = 0; u < 4; ++u) b[u] = (short)f2bf(tileS[c8+4+u][rn]);
    int gA = (k0 + c8) >> 2;
    *(s16x4*)(outT + (size_t)(n0+rn)*QL + perm4(gA)*4)   = a;
    *(s16x4*)(outT + (size_t)(n0+rn)*QL + perm4(gA+1)*4) = b;
  }
}

// ---------------- wk + wp -> [192][7168] bf16 linear ----------------
__global__ __launch_bounds__(256) void k_trkw(const float* __restrict__ wk,
                                              const float* __restrict__ wp,
                                              unsigned short* __restrict__ wkpT) {
  __shared__ float tileS[64][65];
  int bx = blockIdx.x;
  int k0 = blockIdx.y*64;
  int tid = threadIdx.x;
  const float* src; int stride, c0;
  if (bx < 2) { src = wk; stride = DD; c0 = bx*64; }
  else        { src = wp; stride = NH; c0 = 0; }
  for (int c = tid; c < 1024; c += 256) {
    int r = c >> 4, c4 = (c & 15)*4;
    float4 v = *(const float4*)(src + (size_t)(k0+r)*stride + c0 + c4);
    tileS[r][c4] = v.x; tileS[r][c4+1] = v.y; tileS[r][c4+2] = v.z; tileS[r][c4+3] = v.w;
  }
  __syncthreads();
  int rowOff = bx*64;
  for (int c = tid; c < 512; c += 256) {
    int rn = c >> 3, c8 = (c & 7)*8;
    s16x8 v;
    #pragma unroll
    for (int u = 0; u < 8; ++u) v[u] = (short)f2bf(tileS[c8+u][rn]);
    *(s16x8*)(wkpT + (size_t)(rowOff+rn)*HID + k0 + c8) = v;
  }
}

// ---------------- q = qr @ wq_b : MFMA GEMM, gload_lds + swizzled frag layout ----------------
__global__ __launch_bounds__(256) void k_gemm_q(const unsigned short* __restrict__ qrb,
                                                const unsigned short* __restrict__ wqbt,
                                                const float2* __restrict__ trig,
                                                unsigned short* __restrict__ qb) {
  __shared__ __align__(16) unsigned short As[128*64];
  __shared__ __align__(16) unsigned short Bs[128*64];
  int tid = threadIdx.x;
  int w = tid >> 6, wr = w >> 1, wc = w & 1, l = tid & 63, lg = l >> 4, lm = l & 15;
  int m0 = blockIdx.y*128, n0 = blockIdx.x*128;
  f32x4 acc[4][4] = {};
  for (int k0 = 0; k0 < QL; k0 += 64) {
    __syncthreads();
    #pragma unroll
    for (int u = 0; u < 4; ++u) {
      int c = tid + 256*u;
      int row = c >> 3, cp = c & 7;
      int srcc = (cp ^ (row & 7)) * 8;
      __builtin_amdgcn_global_load_lds(
        (const __attribute__((address_space(1))) unsigned int*)(qrb + (size_t)(m0+row)*QL + k0 + srcc),
        (__attribute__((address_space(3))) unsigned int*)(As + (size_t)c*8), 16, 0, 0);
    }
    #pragma unroll
    for (int u = 0; u < 4; ++u) {
      int c = tid + 256*u;
      int row = c >> 3, cp = c & 7;
      int srcc = (cp ^ (row & 7)) * 8;
      __builtin_amdgcn_global_load_lds(
        (const __attribute__((address_space(1))) unsigned int*)(wqbt + (size_t)(n0+row)*QL + k0 + srcc),
        (__attribute__((address_space(3))) unsigned int*)(Bs + (size_t)c*8), 16, 0, 0);
    }
    __syncthreads();
    #pragma unroll
    for (int kk = 0; kk < 2; ++kk) {
      s16x8 af[4], bfr[4];
      #pragma unroll
      for (int i = 0; i < 4; ++i) {
        int row = wr*64 + i*16 + lm;
        int ch = (kk*4 + lg) ^ (row & 7);
        af[i] = *(const s16x8*)(As + row*64 + ch*8);
      }
      #pragma unroll
      for (int j = 0; j < 4; ++j) {
        int row = wc*64 + j*16 + lm;
        int ch = (kk*4 + lg) ^ (row & 7);
        bfr[j] = *(const s16x8*)(Bs + row*64 + ch*8);
      }
      #pragma unroll
      for (int i = 0; i < 4; ++i)
        #pragma unroll
        for (int j = 0; j < 4; ++j)
          acc[i][j] = __builtin_amdgcn_mfma_f32_16x16x32_bf16(af[i], bfr[j], acc[i][j], 0, 0, 0);
    }
  }
  #pragma unroll
  for (int i = 0; i < 4; ++i) {
    int trow = m0 + wr*64 + i*16 + lg*4;
    if (wc == 0) {
      #pragma unroll
      for (int r = 0; r < 4; ++r) {
        int t = trow + r;
        #pragma unroll
        for (int jj = 0; jj < 2; ++jj) {
          int idx = jj*16 + lm;
          float2 cs = trig[t*32 + idx];
          float x1 = acc[i][jj][r], x2 = acc[i][jj+2][r];
          acc[i][jj][r]   = x1*cs.x - x2*cs.y;
          acc[i][jj+2][r] = x2*cs.x + x1*cs.y;
        }
      }
    }
    #pragma unroll
    for (int j = 0; j < 4; ++j)
      #pragma unroll
      for (int r = 0; r < 4; ++r)
        qb[(size_t)(trow + r)*NQ + n0 + wc*64 + j*16 + lm] = f2bf(acc[i][j][r]);
  }
}

// ---------------- fused k + w_proj GEMM via bf16 MFMA, split-K 8 ----------------
__global__ __launch_bounds__(256) void k_kw_mfma(const unsigned short* __restrict__ hb,
                                                 const unsigned short* __restrict__ wkpT,
                                                 float* __restrict__ kpart) {
  __shared__ unsigned short As[32*68];
  __shared__ unsigned short Bs[192*68];
  int tid = threadIdx.x;
  int w = tid >> 6, l = tid & 63, lg = l >> 4, lm = l & 15;
  int ks = blockIdx.x, m0 = blockIdx.y*32;
  int kbase = ks*896;
  f32x4 acc[2][3] = {};
  for (int k0 = 0; k0 < 896; k0 += 64) {
    __syncthreads();
    for (int c = tid; c < 1792; c += 256) {
      int row = c >> 3, col8 = (c & 7)*8;
      if (row < 32)
        cp16(&As[row*68 + col8], hb + (size_t)(m0+row)*HID + kbase + k0 + col8);
      else
        cp16(&Bs[(row-32)*68 + col8], wkpT + (size_t)(row-32)*HID + kbase + k0 + col8);
    }
    __syncthreads();
    #pragma unroll
    for (int kk = 0; kk < 2; ++kk) {
      int kb = kk*32 + 4*lg;
      s16x8 af[2], bfr[3];
      #pragma unroll
      for (int i = 0; i < 2; ++i) af[i] = ld_frag(&As[(i*16 + lm)*68 + kb]);
      #pragma unroll
      for (int j = 0; j < 3; ++j) bfr[j] = ld_frag(&Bs[(w*48 + j*16 + lm)*68 + kb]);
      #pragma unroll
      for (int i = 0; i < 2; ++i)
        #pragma unroll
        for (int j = 0; j < 3; ++j)
          acc[i][j] = __builtin_amdgcn_mfma_f32_16x16x32_bf16(af[i], bfr[j], acc[i][j], 0, 0, 0);
    }
  }
  #pragma unroll
  for (int i = 0; i < 2; ++i)
    #pragma unroll
    for (int j = 0; j < 3; ++j)
      #pragma unroll
      for (int r = 0; r < 4; ++r) {
        int row = m0 + i*16 + lg*4 + r, col = w*48 + j*16 + lm;
        kpart[(size_t)ks*TT*192 + (size_t)row*192 + col] = acc[i][j][r];
      }
}

// ---------------- wc[t,h] ----------------
__global__ void k_post_w(const float* __restrict__ kpart,
                         const float* __restrict__ bp,
                         float* __restrict__ wcq) {
  int g = blockIdx.x*256 + threadIdx.x;
  int t = g >> 6, h = g & 63;
  float s = 0.f;
  for (int ks = 0; ks < 8; ++ks)
    s += kpart[(size_t)ks*TT*192 + (size_t)t*192 + 128 + h];
  s = (s + bp[h]) * 0.08838834764831845f;
  wcq[t*64 + h] = s * 0.125f;
}

// ---------------- k partials -> LN -> RoPE -> bf16 (frag-permuted d) ----------------
__global__ __launch_bounds__(128) void k_post_k(const float* __restrict__ kpart,
                                                const float* __restrict__ kg,
                                                const float* __restrict__ kb,
                                                const float2* __restrict__ trig,
                                                unsigned short* __restrict__ kkb) {
  __shared__ float red[128];
  __shared__ float row[128];
  int t = blockIdx.x, d = threadIdx.x;
  float v = 0.f;
  for (int ks = 0; ks < 8; ++ks)
    v += kpart[(size_t)ks*TT*192 + (size_t)t*192 + d];
  red[d] = v; __syncthreads();
  for (int off = 64; off; off >>= 1) { if (d < off) red[d] += red[d+off]; __syncthreads(); }
  float mu = red[0] * (1.f/128.f); __syncthreads();
  float diff = v - mu;
  red[d] = diff*diff; __syncthreads();
  for (int off = 64; off; off >>= 1) { if (d < off) red[d] += red[d+off]; __syncthreads(); }
  float var = red[0] * (1.f/128.f);
  float rsq = 1.f / sqrtf(var + 1e-6f);
  float kn = (v - mu) * rsq * kg[d] + kb[d];
  row[d] = kn; __syncthreads();
  float outv;
  if (d < 32) {
    float2 cs = trig[t*32 + d];
    outv = row[d]*cs.x - row[d+32]*cs.y;
  } else if (d < 64) {
    float2 cs = trig[t*32 + d - 32];
    outv = row[d]*cs.x + row[d-32]*cs.y;
  } else outv = kn;
  // frag-permute within each 32-d block: logical r=pc*16+lg*4+e -> phys lg*8+pc*4+e
  int r = d & 31;
  int phys = (d & ~31) + ((r & 15) >> 2)*8 + (r >> 4)*4 + (r & 3);
  kkb[(size_t)t*DD + phys] = f2bf(outv);
}

// ---------------- scores: K direct-from-L2, MFMA, register bitonic top-512 ----------------
__global__ __launch_bounds__(512) void k_scores(const unsigned short* __restrict__ qb,
                                                const unsigned short* __restrict__ kkb,
                                                const float* __restrict__ wcq,
                                                const int* __restrict__ pos,
                                                float* __restrict__ out) {
  __shared__ unsigned short Qs[64*132];     // 16.9 KB
  __shared__ unsigned long long keys[1024]; // 8 KB
  int tid = threadIdx.x;
  int bid = blockIdx.x;
  int t = (bid & 1) ? (1023 - (bid >> 1)) : (bid >> 1);
  int w = tid >> 6, l = tid & 63, lg = l >> 4, lm = l & 15;
  keys[tid] = packkey(NEGF, tid);
  keys[tid + 512] = packkey(NEGF, tid + 512);
  for (int c = tid; c < 1024; c += 512) {
    int h = c >> 4, d8 = (c & 15)*8;
    cp16(&Qs[h*132 + d8], qb + (size_t)t*NQ + h*DD + d8);
  }
  float wreg[4];
  #pragma unroll
  for (int j = 0; j < 4; ++j) wreg[j] = wcq[t*64 + j*16 + lm];
  int post = pos[t];
  int niter = (t >> 7) + 1;
  __syncthreads();
  for (int it = 0; it < niter; ++it) {
    int s0 = it << 7;
    const unsigned short* kbase = kkb + (size_t)(s0 + w*16 + lm)*DD;
    f32x4 acc[4] = {};
    #pragma unroll
    for (int ksb = 0; ksb < 4; ++ksb) {
      s16x8 af = *(const s16x8*)(kbase + ksb*32 + lg*8);   // frag-permuted global K
      int kbd = ksb*32 + 4*lg;
      #pragma unroll
      for (int j = 0; j < 4; ++j) {
        s16x8 bfr = ld_frag(&Qs[(j*16 + lm)*132 + kbd]);
        acc[j] = __builtin_amdgcn_mfma_f32_16x16x32_bf16(af, bfr, acc[j], 0, 0, 0);
      }
    }
    #pragma unroll
    for (int r = 0; r < 4; ++r) {
      float p = 0.f;
      #pragma unroll
      for (int j = 0; j < 4; ++j) p += fmaxf(acc[j][r], 0.f) * wreg[j];
      p += __shfl_xor(p, 1); p += __shfl_xor(p, 2);
      p += __shfl_xor(p, 4); p += __shfl_xor(p, 8);
      if (lm == 0) {
        int s = s0 + w*16 + lg*4 + r;
        keys[s] = packkey((post >= pos[s]) ? p : NEGF, s);
      }
    }
  }
  __syncthreads();
  // register bitonic: thread holds elements tid (r0) and tid+512 (r1)
  unsigned long long r0 = keys[tid], r1 = keys[tid + 512];
  for (int kk = 2; kk <= 512; kk <<= 1) {
    for (int j = kk >> 1; j >= 64; j >>= 1) {          // cross-wave: LDS
      keys[tid] = r0; keys[tid + 512] = r1;
      __syncthreads();
      unsigned long long o0 = keys[tid ^ j];
      unsigned long long o1 = keys[(tid + 512) ^ j];
      bool lowp = (tid & j) == 0;
      bool asc0 = (tid & kk) == 0;
      bool asc1 = ((tid + 512) & kk) == 0;
      r0 = (lowp == asc0) ? (r0 < o0 ? r0 : o0) : (r0 > o0 ? r0 : o0);
      r1 = (lowp == asc1) ? (r1 < o1 ? r1 : o1) : (r1 > o1 ? r1 : o1);
      __syncthreads();
    }
    int jstart = (kk >> 1) < 32 ? (kk >> 1) : 32;
    for (int j = jstart; j >= 1; j >>= 1) {            // intra-wave: shfl
      unsigned long long o0 = shfl_xor_u64(r0, j);
      unsigned long long o1 = shfl_xor_u64(r1, j);
      bool lowp = (tid & j) == 0;
      bool asc0 = (tid & kk) == 0;
      bool asc1 = ((tid + 512) & kk) == 0;
      r0 = (lowp == asc0) ? (r0 < o0 ? r0 : o0) : (r0 > o0 ? r0 : o0);
      r1 = (lowp == asc1) ? (r1 < o1 ? r1 : o1) : (r1 > o1 ? r1 : o1);
    }
  }
  // split j=512 (ascending): intra-thread
  {
    unsigned long long mn = r0 < r1 ? r0 : r1;
    unsigned long long mx = r0 < r1 ? r1 : r0;
    r0 = mn; r1 = mx;
  }
  // half-merge of lower 512 (all ascending): j=256,128,64 via LDS, j<=32 via shfl
  for (int j = 256; j >= 64; j >>= 1) {
    keys[tid] = r0; keys[tid + 512] = r1;
    __syncthreads();
    unsigned long long o0 = keys[tid ^ j];
    unsigned long long o1 = keys[(tid + 512) ^ j];
    bool lowp = (tid & j) == 0;
    r0 = lowp ? (r0 < o0 ? r0 : o0) : (r0 > o0 ? r0 : o0);
    r1 = lowp ? (r1 < o1 ? r1 : o1) : (r1 > o1 ? r1 : o1);
    __syncthreads();
  }
  for (int j = 32; j >= 1; j >>= 1) {
    unsigned long long o0 = shfl_xor_u64(r0, j);
    bool lowp = (tid & j) == 0;
    r0 = lowp ? (r0 < o0 ? r0 : o0) : (r0 > o0 ? r0 : o0);
  }
  {
    float v = unpackval(r0);
    out[(size_t)t*TOPK + tid] = v;
    out[(size_t)TT*TOPK + (size_t)t*TOPK + tid] =
        (v > 0.5f*NEGF) ? (float)(unsigned int)(r0 & 0xFFFFFFFFu) : -1.0f;
  }
}

extern "C" void kernel_launch(void* const* d_in, const int* in_sizes, int n_in,
                              void* d_out, int out_size, void* d_ws, size_t ws_size,
                              hipStream_t stream) {
  const float* hidden = (const float*)d_in[0];
  const float* qr     = (const float*)d_in[1];
  const float* wqb    = (const float*)d_in[2];
  const float* wk     = (const float*)d_in[3];
  const float* kg     = (const float*)d_in[4];
  const float* kb     = (const float*)d_in[5];
  const float* wp     = (const float*)d_in[6];
  const float* bp     = (const float*)d_in[7];
  const int*   pos    = (const int*)d_in[8];
  float* out = (float*)d_out;

  char* W = (char*)d_ws;
  unsigned short* qbuf  = (unsigned short*)(W + OFF_QB);
  unsigned short* wqbt  = (unsigned short*)(W + OFF_WQBT);
  unsigned short* qrb   = (unsigned short*)(W + OFF_QRB);
  float*          kpart = (float*)(W + OFF_KPART);
  unsigned short* kkbuf = (unsigned short*)(W + OFF_KKB);
  float*          wcq   = (float*)(W + OFF_WC);
  float2*         trig  = (float2*)(W + OFF_TRIG);
  unsigned short* hb    = (unsigned short*)(W + OFF_HB);
  unsigned short* wkpT  = (unsigned short*)(W + OFF_WKPT);

  k_trig   <<<TT, 32, 0, stream>>>(pos, trig);
  k_cvtp   <<<(TT*QL/4)/256, 256, 0, stream>>>(qr, qrb);
  k_cvt    <<<(TT*HID)/1024, 256, 0, stream>>>(hidden, hb);
  k_trcvt  <<<dim3(NQ/64, QL/64), 256, 0, stream>>>(wqb, wqbt);
  k_trkw   <<<dim3(3, HID/64), 256, 0, stream>>>(wk, wp, wkpT);
  k_gemm_q <<<dim3(NQ/128, TT/128), 256, 0, stream>>>(qrb, wqbt, trig, qbuf);
  k_kw_mfma<<<dim3(8, TT/32), 256, 0, stream>>>(hb, wkpT, kpart);
  k_post_w <<<(TT*NH)/256, 256, 0, stream>>>(kpart, bp, wcq);
  k_post_k <<<TT, 128, 0, stream>>>(kpart, kg, kb, trig, kkbuf);
  k_scores <<<TT, 512, 0, stream>>>(qbuf, kkbuf, wcq, pos, out);
}